// Round 11
// baseline (842.741 us; speedup 1.0000x reference)
//
#include <hip/hip_runtime.h>
#include <hip/hip_bf16.h>

#define B_   4
#define L_   2048
#define DM   512
#define DI   1024
#define NST  16
#define DTR  32
#define ROWS (B_ * L_)   // 8192
#define NCHUNK 64
#define CLEN  (L_ / NCHUNK)   // 32
#define LN2R 1.4426950408889634f

typedef unsigned short u16;
typedef __attribute__((ext_vector_type(8))) short bf16x8;
typedef __attribute__((ext_vector_type(4))) float f32x4;
typedef __attribute__((ext_vector_type(4))) float float4v;
typedef __attribute__((ext_vector_type(2))) float f32x2;

__device__ __forceinline__ float bf2f(u16 h) {
  union { unsigned int u; float f; } v; v.u = ((unsigned int)h) << 16; return v.f;
}
__device__ __forceinline__ u16 f2bf(float f) {
  union { float f; unsigned int u; } v; v.f = f;
  unsigned int u = v.u;
  if ((u & 0x7fffffffu) > 0x7f800000u) return (u16)((u >> 16) | 0x0040u);
  return (u16)((u + 0x7fffu + ((u >> 16) & 1u)) >> 16);
}
__device__ __forceinline__ float sigmoidf_(float x) { return 1.f / (1.f + __expf(-x)); }

// packed f32 ops (MI355X full-rate fp32 = v_pk_*_f32)
__device__ __forceinline__ f32x2 pk_mul(f32x2 a, f32x2 b) {
  f32x2 d; asm("v_pk_mul_f32 %0, %1, %2" : "=v"(d) : "v"(a), "v"(b)); return d;
}
__device__ __forceinline__ f32x2 pk_fma(f32x2 a, f32x2 b, f32x2 c) {
  f32x2 d; asm("v_pk_fma_f32 %0, %1, %2, %3" : "=v"(d) : "v"(a), "v"(b), "v"(c)); return d;
}

// async global->LDS, 16B per lane; dest = wave-uniform base + lane*16 (m97 pattern)
__device__ __forceinline__ void gload16(const u16* g, u16* l) {
  __builtin_amdgcn_global_load_lds(
      (const __attribute__((address_space(1))) void*)g,
      (__attribute__((address_space(3))) void*)l, 16, 0, 0);
}

// ---------------- f32 -> bf16 weight conversion ----------------
__global__ __launch_bounds__(256) void cvt_k(const float* __restrict__ in,
                                             u16* __restrict__ out, int n4) {
  int i = blockIdx.x * 256 + threadIdx.x;       // n4 = n/4
  if (i >= n4) return;
  float4v v = *(const float4v*)&in[i * 4];
  u16 o[4];
  o[0] = f2bf(v.x); o[1] = f2bf(v.y); o[2] = f2bf(v.z); o[3] = f2bf(v.w);
  *(ulong1*)&out[i * 4] = *(ulong1*)o;
}

// ---------------- dt_w transpose: [4][DI][DTR] -> [4][DTR][DI] (f32) ----------------
__global__ __launch_bounds__(256) void trp_k(const float* __restrict__ in,
                                             float* __restrict__ out) {
  int o = blockIdx.x * 256 + threadIdx.x;       // 4*DTR*DI = 131072
  int li = o >> 15;
  int k = (o >> 10) & (DTR - 1);
  int d = o & (DI - 1);
  out[o] = in[((size_t)li * DI + d) * DTR + k];
}

// ---------------- embed gather (writes f32 residual) ----------------
__global__ __launch_bounds__(256) void embed_k(const int* __restrict__ ids,
                                               const float* __restrict__ emb,
                                               float* __restrict__ res, int flip) {
  int idx = blockIdx.x * 256 + threadIdx.x;         // ROWS*DM threads
  int c = idx & (DM - 1);
  int row = idx >> 9;
  int b = row >> 11;
  int l = row & (L_ - 1);
  int sl = flip ? (L_ - 1 - l) : l;
  int id = ids[(b << 11) + sl];
  res[idx] = emb[id * DM + c];
}

// ---------------- (res += hid); xn = rmsnorm(res) * w  (bf16 out) ----------------
template <bool ADD>
__global__ __launch_bounds__(256) void addnorm_k(float* __restrict__ res,
                                                 const float* __restrict__ hid,
                                                 const float* __restrict__ w,
                                                 u16* __restrict__ xn) {
  int row = blockIdx.x;
  int tid = threadIdx.x;
  int base = row * DM;
  float x0 = res[base + tid];
  float x1 = res[base + 256 + tid];
  if (ADD) {
    x0 += hid[base + tid];
    x1 += hid[base + 256 + tid];
    res[base + tid] = x0;
    res[base + 256 + tid] = x1;
  }
  float s = x0 * x0 + x1 * x1;
  for (int off = 32; off; off >>= 1) s += __shfl_xor(s, off);
  __shared__ float ps[4];
  if (!(tid & 63)) ps[tid >> 6] = s;
  __syncthreads();
  float tot = ps[0] + ps[1] + ps[2] + ps[3];
  float rs = 1.f / sqrtf(tot / (float)DM + 1e-5f);
  xn[base + tid]       = f2bf(x0 * rs * w[tid]);
  xn[base + 256 + tid] = f2bf(x1 * rs * w[tid + 256]);
}

// ---------------- 256x256-tile GEMM (in_proj): out[m][n] = sum_k A[m][k]*W[n][k] ----------------
// 8 waves (2Mx4N), BK=32, ring-of-3 LDS, ONE barrier/step, counted vmcnt,
// XCD-patch block mapping (grid MUST be 256 = 32 MT x 8 NT): each XCD gets an
// 8Mx4N patch whose A+W working set (~3.1 MB) fits its private 4 MB L2.
__global__ __launch_bounds__(512) void gemm256_k(const u16* __restrict__ A,
                                                 const u16* __restrict__ W,
                                                 u16* __restrict__ outp,
                                                 int N, int K) {
  constexpr int BK = 32;
  __shared__ u16 As[3][256 * BK];                 // 48 kB
  __shared__ u16 Wsh[3][256 * BK];                // 48 kB
  int tid = threadIdx.x;
  int lane = tid & 63;
  int wv = tid >> 6;                              // 0..7
  int wr = wv >> 2, wc = wv & 3;                  // 2 x 4 wave grid
  int bid = blockIdx.x;
  int xcd = bid & 7, jj = bid >> 3;
  int mt = (xcd & 3) * 8 + (jj & 7);              // 0..31
  int nt = (xcd >> 2) * 4 + (jj >> 3);            // 0..7
  int m0 = mt * 256, n0 = nt * 256;
  f32x4 acc[8][4];
#pragma unroll
  for (int i = 0; i < 8; ++i)
#pragma unroll
    for (int j = 0; j < 4; ++j) acc[i][j] = (f32x4){0.f, 0.f, 0.f, 0.f};
  int rr = lane & 15;
  int kk = (lane >> 4) << 3;
  int l4 = lane >> 2;          // 0..15: row within 16-row chunk
  int c8 = (lane & 3) << 3;    // 0,8,16,24: k-col (u16)
  const u16* Ag = A + (size_t)(m0 + l4) * K + c8;
  const u16* Wg = W + (size_t)(n0 + l4) * K + c8;

  auto stage = [&](int k0, int buf) {
    gload16(Ag + (size_t)(wv * 16) * K + k0, &As[buf][wv * 512]);
    gload16(Ag + (size_t)((wv + 8) * 16) * K + k0, &As[buf][(wv + 8) * 512]);
    gload16(Wg + (size_t)(wv * 16) * K + k0, &Wsh[buf][wv * 512]);
    gload16(Wg + (size_t)((wv + 8) * 16) * K + k0, &Wsh[buf][(wv + 8) * 512]);
  };

  int NK = K / BK;                                // 16 for K=512
  stage(0, 0); stage(BK, 1);
  for (int k = 0; k < NK; ++k) {
    if (k < NK - 1)
      asm volatile("s_waitcnt vmcnt(4)" ::: "memory");   // tile k done; k+1 in flight
    else
      asm volatile("s_waitcnt vmcnt(0)" ::: "memory");
    __builtin_amdgcn_s_barrier();
    __builtin_amdgcn_sched_barrier(0);
    if (k + 2 < NK) stage((k + 2) * BK, (k + 2) % 3);
    __builtin_amdgcn_sched_barrier(0);
    int cur = k % 3;
    bf16x8 af[8], wf[4];
#pragma unroll
    for (int mi = 0; mi < 8; ++mi)
      af[mi] = *(bf16x8*)&As[cur][(wr * 128 + mi * 16 + rr) * BK + kk];
#pragma unroll
    for (int ni = 0; ni < 4; ++ni)
      wf[ni] = *(bf16x8*)&Wsh[cur][(wc * 64 + ni * 16 + rr) * BK + kk];
#pragma unroll
    for (int mi = 0; mi < 8; ++mi)
#pragma unroll
      for (int ni = 0; ni < 4; ++ni)
        acc[mi][ni] = __builtin_amdgcn_mfma_f32_16x16x32_bf16(af[mi], wf[ni], acc[mi][ni], 0, 0, 0);
    // waves' ds_reads complete before they reach the next barrier (MFMA operand
    // interlock), so buf[cur] may be overwritten by a stage issued after it.
  }
  int cr = (lane >> 4) << 2;
  int cc = lane & 15;
#pragma unroll
  for (int mi = 0; mi < 8; ++mi)
#pragma unroll
    for (int ni = 0; ni < 4; ++ni) {
      int row = m0 + wr * 128 + mi * 16 + cr;
      int col = n0 + wc * 64 + ni * 16 + cc;
#pragma unroll
      for (int j = 0; j < 4; ++j)
        outp[(size_t)(row + j) * N + col] = f2bf(acc[mi][ni][j]);
    }
}

// ---------------- GEMM (generic): 4-buffer ring, stage-ahead-3, one barrier/step ----------------
#define EPI_F32  0
#define EPI_BF16 1
#define EPI_BIAS 2

template <int BN, int EPI, int SK = 1>
__global__ __launch_bounds__(256) void gemm_bt(const u16* __restrict__ A,
                                               const u16* __restrict__ W,
                                               void* __restrict__ outp,
                                               const float* __restrict__ bias,
                                               int N, int K) {
  constexpr int BM = 128, BK = 32;
  constexpr int NF = BN / 32;                      // n-frags per wave
  constexpr int G = (BN == 128) ? 4 : 3;           // gloads per wave per stage
  __shared__ u16 As[4][BM * BK];                   // 4 x 8 kB
  __shared__ u16 Wsh[4][BN * BK];
  int tid = threadIdx.x;
  int lane = tid & 63;
  int wv = tid >> 6;
  int wr = wv >> 1, wc = wv & 1;
  int m0 = blockIdx.x * BM;
  int n0 = (SK > 1) ? 0 : blockIdx.y * BN;
  int koff = (SK > 1) ? blockIdx.y * (K / SK) : 0;
  int KS = K / SK;
  int NK = KS / BK;
  f32x4 acc[4][NF];
#pragma unroll
  for (int i = 0; i < 4; ++i)
#pragma unroll
    for (int j = 0; j < NF; ++j) acc[i][j] = (f32x4){0.f, 0.f, 0.f, 0.f};
  int rr = lane & 15;
  int kk = (lane >> 4) << 3;
  int l4 = lane >> 2;          // 0..15: row within 16-row chunk
  int c8 = (lane & 3) << 3;    // 0,8,16,24: k-col (u16)
  const u16* Ag = A + (size_t)(m0 + l4) * K + koff + c8;
  const u16* Wg = W + (size_t)(n0 + l4) * K + koff + c8;

  auto stage = [&](int k0, int buf) {
    gload16(Ag + (size_t)(wv * 16) * K + k0, &As[buf][wv * 512]);
    gload16(Ag + (size_t)((wv + 4) * 16) * K + k0, &As[buf][(wv + 4) * 512]);
    gload16(Wg + (size_t)(wv * 16) * K + k0, &Wsh[buf][wv * 512]);
    if (BN == 128)
      gload16(Wg + (size_t)((wv + 4) * 16) * K + k0, &Wsh[buf][(wv + 4) * 512]);
  };

  stage(0, 0); stage(BK, 1); stage(2 * BK, 2);     // NK >= 8 always
  for (int k = 0; k < NK; ++k) {
    if (k < NK - 2)
      asm volatile("s_waitcnt vmcnt(%0)" :: "n"(2 * G) : "memory");
    else if (k == NK - 2)
      asm volatile("s_waitcnt vmcnt(%0)" :: "n"(G) : "memory");
    else
      asm volatile("s_waitcnt vmcnt(0)" ::: "memory");
    __builtin_amdgcn_s_barrier();
    __builtin_amdgcn_sched_barrier(0);
    if (k + 3 < NK) stage((k + 3) * BK, (k + 3) & 3);
    __builtin_amdgcn_sched_barrier(0);
    int cur = k & 3;
    bf16x8 af[4], wf[NF];
#pragma unroll
    for (int mi = 0; mi < 4; ++mi)
      af[mi] = *(bf16x8*)&As[cur][(wr * 64 + mi * 16 + rr) * BK + kk];
#pragma unroll
    for (int ni = 0; ni < NF; ++ni)
      wf[ni] = *(bf16x8*)&Wsh[cur][(wc * (BN / 2) + ni * 16 + rr) * BK + kk];
#pragma unroll
    for (int mi = 0; mi < 4; ++mi)
#pragma unroll
      for (int ni = 0; ni < NF; ++ni)
        acc[mi][ni] = __builtin_amdgcn_mfma_f32_16x16x32_bf16(af[mi], wf[ni], acc[mi][ni], 0, 0, 0);
  }
  int cr = (lane >> 4) << 2;
  int cc = lane & 15;
  float* outF = (float*)outp + ((SK > 1) ? (size_t)blockIdx.y * (size_t)ROWS * N : 0);
#pragma unroll
  for (int mi = 0; mi < 4; ++mi)
#pragma unroll
    for (int ni = 0; ni < NF; ++ni) {
      int row = m0 + wr * 64 + mi * 16 + cr;
      int col = n0 + wc * (BN / 2) + ni * 16 + cc;
      float bv = (EPI == EPI_BIAS) ? bias[col] : 0.f;
#pragma unroll
      for (int j = 0; j < 4; ++j) {
        float v = acc[mi][ni][j] + bv;
        if (EPI == EPI_BF16)
          ((u16*)outp)[(size_t)(row + j) * N + col] = f2bf(v);
        else
          outF[(size_t)(row + j) * N + col] = v;
      }
    }
}

// ---------------- depthwise causal conv (k=4) + bias + SiLU (bf16 out) ----------------
__global__ __launch_bounds__(256) void conv_k(const u16* __restrict__ xz,
                                              const float* __restrict__ cw,
                                              const float* __restrict__ cb,
                                              u16* __restrict__ uh) {
  int idx = blockIdx.x * 256 + threadIdx.x;        // ROWS*DI
  int c = idx & (DI - 1);
  int row = idx >> 10;
  int l = row & (L_ - 1);
  float acc = cb[c];
#pragma unroll
  for (int j = 0; j < 4; ++j) {
    int ls = l + j - 3;
    if (ls >= 0)
      acc += bf2f(xz[(size_t)(row + j - 3) * (2 * DI) + c]) * cw[c * 4 + j];
  }
  float s = acc * sigmoidf_(acc);
  uh[idx] = f2bf(s);
}

// A-structure check: A[n] == (n+1)*A[0] (true for A_log = log(1..16))
__device__ __forceinline__ bool a_fast(const float* alog, int d, float& a20) {
  a20 = -__expf(alog[d * NST]) * LN2R;
  bool fast = true;
#pragma unroll
  for (int n = 1; n < NST; ++n) {
    float an = -__expf(alog[d * NST + n]) * LN2R;
    fast &= (fabsf(an - (float)(n + 1) * a20) <= 1e-5f * (float)(n + 1) * fabsf(a20));
  }
  return fast;
}

// stage xs[32][64] by summing 4 x_proj split-K partials
__device__ __forceinline__ void stage_xs(float (*xs)[64], const float* xp,
                                         int b, int t0, int tid) {
  size_t base = ((size_t)b * L_ + t0) * 64;
  const float4v* s0 = (const float4v*)(xp + base);
  const float4v* s1 = (const float4v*)(xp + (size_t)ROWS * 64 + base);
  const float4v* s2 = (const float4v*)(xp + (size_t)2 * ROWS * 64 + base);
  const float4v* s3 = (const float4v*)(xp + (size_t)3 * ROWS * 64 + base);
  float4v* dst = (float4v*)&xs[0][0];
  dst[tid]       = s0[tid]       + s1[tid]       + s2[tid]       + s3[tid];
  dst[tid + 256] = s0[tid + 256] + s1[tid + 256] + s2[tid + 256] + s3[tid + 256];
}

// ---------------- fused dt-projection + scan pass 1 ----------------
__global__ __launch_bounds__(256) void dtscan1_k(const u16* __restrict__ uh,
                                                 const float* __restrict__ xp,
                                                 const float* __restrict__ dtw_t,
                                                 const float* __restrict__ dtb,
                                                 const float* __restrict__ alog,
                                                 float* __restrict__ dtf,
                                                 float* __restrict__ chk) {
  __shared__ float xs[CLEN][64];                  // 8 kB
  int blk = blockIdx.x;            // B*NCHUNK*(DI/256) = 1024
  int db = blk & 3;
  int c  = (blk >> 2) & (NCHUNK - 1);
  int b  = blk >> 8;
  int tid = threadIdx.x;
  int d  = db * 256 + tid;
  int t0 = c * CLEN;
  stage_xs(xs, xp, b, t0, tid);
  f32x2 w2[16];
#pragma unroll
  for (int j = 0; j < 16; ++j)
    w2[j] = (f32x2){dtw_t[(size_t)(2 * j) * DI + d], dtw_t[(size_t)(2 * j + 1) * DI + d]};
  float bias = dtb[d];
  float a20;
  bool fast = a_fast(alog, d, a20);
  __syncthreads();
  float S = 0.f;
  size_t ubase = ((size_t)b * L_ + t0) * DI + d;
  f32x2 h2[8];
#pragma unroll
  for (int q = 0; q < 8; ++q) h2[q] = (f32x2){0.f, 0.f};
  for (int t = 0; t < CLEN; ++t) {
    f32x2 a2 = {bias, 0.f};
    const f32x2* xr2 = (const f32x2*)&xs[t][0];
#pragma unroll
    for (int j = 0; j < 16; ++j) a2 = pk_fma(xr2[j], w2[j], a2);
    float a = a2.x + a2.y;
    float dtv = (a > 15.f) ? a : __logf(1.f + __expf(a));
    dtf[ubase] = dtv;
    float du = dtv * bf2f(uh[ubase]);
    S += dtv;
    if (fast) {
      float p1 = exp2f(dtv * a20);
      float p2 = p1 * p1;
      f32x2 pw = {p1, p2};
      f32x2 pst = {p2, p2};
      f32x2 du2 = {du, du};
#pragma unroll
      for (int k = 0; k < 4; ++k) {
        f32x4 bv = *(const f32x4*)&xs[t][DTR + k * 4];
        f32x2 blo = __builtin_shufflevector(bv, bv, 0, 1);
        f32x2 bhi = __builtin_shufflevector(bv, bv, 2, 3);
        h2[2 * k]     = pk_fma(pw, h2[2 * k], pk_mul(du2, blo));
        pw = pk_mul(pw, pst);
        h2[2 * k + 1] = pk_fma(pw, h2[2 * k + 1], pk_mul(du2, bhi));
        if (k < 3) pw = pk_mul(pw, pst);
      }
    } else {
#pragma unroll
      for (int q = 0; q < 8; ++q) {
        float e0 = exp2f(dtv * -__expf(alog[d * NST + 2 * q]) * LN2R);
        float e1 = exp2f(dtv * -__expf(alog[d * NST + 2 * q + 1]) * LN2R);
        f32x2 bv = *(const f32x2*)&xs[t][DTR + q * 2];
        h2[q] = pk_fma((f32x2){e0, e1}, h2[q], pk_mul((f32x2){du, du}, bv));
      }
    }
    ubase += DI;
  }
  const size_t H = (size_t)B_ * NCHUNK * DI * NST;
  size_t idx = ((size_t)(b * NCHUNK + c) * DI + d) * NST;
#pragma unroll
  for (int n = 0; n < NST; ++n) {
    float an = -__expf(alog[d * NST + n]) * LN2R;
    chk[idx + n]     = exp2f(an * S);
    chk[H + idx + n] = (n & 1) ? h2[n >> 1].y : h2[n >> 1].x;
  }
}

// pass 2: per (b,d,n): sequential combine over chunks; overwrite chk_h with start states
__global__ __launch_bounds__(256) void scan2_k(float* __restrict__ chk) {
  int j = blockIdx.x * 256 + threadIdx.x;   // 65536 = B*DI*NST
  int n = j & 15;
  int d = (j >> 4) & (DI - 1);
  int b = j >> 14;
  const size_t H = (size_t)B_ * NCHUNK * DI * NST;
  float h = 0.f;
  for (int c = 0; c < NCHUNK; ++c) {
    size_t idx = ((size_t)(b * NCHUNK + c) * DI + d) * NST + n;
    float a = chk[idx];
    float hl = chk[H + idx];
    chk[H + idx] = h;               // start state for this chunk
    h = a * h + hl;
  }
}

// pass 3: re-run chunk from true start state; fused gate -> bf16 yg
__global__ __launch_bounds__(256) void scan3_k(const u16* __restrict__ uh,
                                               const float* __restrict__ dtf,
                                               const float* __restrict__ xp,
                                               const float* __restrict__ alog,
                                               const float* __restrict__ dvec,
                                               const float* __restrict__ chk,
                                               const u16* __restrict__ xz,
                                               u16* __restrict__ yg) {
  __shared__ float xs[CLEN][64];                  // 8 kB
  int blk = blockIdx.x;            // 1024
  int db = blk & 3;
  int c  = (blk >> 2) & (NCHUNK - 1);
  int b  = blk >> 8;
  int tid = threadIdx.x;
  int d  = db * 256 + tid;
  int t0 = c * CLEN;
  stage_xs(xs, xp, b, t0, tid);
  float a20;
  bool fast = a_fast(alog, d, a20);
  const size_t H = (size_t)B_ * NCHUNK * DI * NST;
  size_t cidx = ((size_t)(b * NCHUNK + c) * DI + d) * NST;
  f32x2 h2[8];
#pragma unroll
  for (int q = 0; q < 8; ++q) h2[q] = *(const f32x2*)&chk[H + cidx + 2 * q];
  float Dv = dvec[d];
  __syncthreads();
  size_t ubase = ((size_t)b * L_ + t0) * DI + d;
  size_t zbase = ((size_t)b * L_ + t0) * (2 * DI) + DI + d;
  if (fast) {
    for (int t = 0; t < CLEN; ++t) {
      float dtv = dtf[ubase];
      float uv  = bf2f(uh[ubase]);
      float du  = dtv * uv;
      float p1 = exp2f(dtv * a20);
      float p2 = p1 * p1;
      f32x2 pw = {p1, p2};
      f32x2 pst = {p2, p2};
      f32x2 du2 = {du, du};
      f32x2 acc2 = {0.f, 0.f};
#pragma unroll
      for (int k = 0; k < 4; ++k) {
        f32x4 bv = *(const f32x4*)&xs[t][DTR + k * 4];
        f32x4 cv = *(const f32x4*)&xs[t][DTR + NST + k * 4];
        f32x2 blo = __builtin_shufflevector(bv, bv, 0, 1);
        f32x2 bhi = __builtin_shufflevector(bv, bv, 2, 3);
        f32x2 clo = __builtin_shufflevector(cv, cv, 0, 1);
        f32x2 chi = __builtin_shufflevector(cv, cv, 2, 3);
        h2[2 * k]     = pk_fma(pw, h2[2 * k], pk_mul(du2, blo));
        acc2          = pk_fma(h2[2 * k], clo, acc2);
        pw = pk_mul(pw, pst);
        h2[2 * k + 1] = pk_fma(pw, h2[2 * k + 1], pk_mul(du2, bhi));
        acc2          = pk_fma(h2[2 * k + 1], chi, acc2);
        if (k < 3) pw = pk_mul(pw, pst);
      }
      float y = acc2.x + acc2.y + uv * Dv;
      float z = bf2f(xz[zbase]);
      yg[ubase] = f2bf(y * z * sigmoidf_(z));
      ubase += DI; zbase += 2 * DI;
    }
  } else {
    float A2[NST];
#pragma unroll
    for (int n = 0; n < NST; ++n) A2[n] = -__expf(alog[d * NST + n]) * LN2R;
    for (int t = 0; t < CLEN; ++t) {
      float dtv = dtf[ubase];
      float uv  = bf2f(uh[ubase]);
      float du  = dtv * uv;
      f32x2 acc2 = {0.f, 0.f};
#pragma unroll
      for (int q = 0; q < 8; ++q) {
        f32x2 bv = *(const f32x2*)&xs[t][DTR + q * 2];
        f32x2 cv = *(const f32x2*)&xs[t][DTR + NST + q * 2];
        f32x2 e = {exp2f(dtv * A2[2 * q]), exp2f(dtv * A2[2 * q + 1])};
        h2[q] = pk_fma(e, h2[q], pk_mul((f32x2){du, du}, bv));
        acc2 = pk_fma(h2[q], cv, acc2);
      }
      float y = acc2.x + acc2.y + uv * Dv;
      float z = bf2f(xz[zbase]);
      yg[ubase] = f2bf(y * z * sigmoidf_(z));
      ubase += DI; zbase += 2 * DI;
    }
  }
}

// ---------------- final rmsnorm(hid+res) -> concat buffer (with flip for dir 1) ----------------
__global__ __launch_bounds__(256) void fincat_k(const float* __restrict__ hid,
                                                const float* __restrict__ res,
                                                const float* __restrict__ w,
                                                u16* __restrict__ cat, int dir) {
  int row = blockIdx.x;
  int tid = threadIdx.x;
  int base = row * DM;
  float x0 = hid[base + tid] + res[base + tid];
  float x1 = hid[base + 256 + tid] + res[base + 256 + tid];
  float s = x0 * x0 + x1 * x1;
  for (int off = 32; off; off >>= 1) s += __shfl_xor(s, off);
  __shared__ float ps[4];
  if (!(tid & 63)) ps[tid >> 6] = s;
  __syncthreads();
  float tot = ps[0] + ps[1] + ps[2] + ps[3];
  float rs = 1.f / sqrtf(tot / (float)DM + 1e-5f);
  int b = row >> 11, l = row & (L_ - 1);
  size_t drow = dir ? ((size_t)(b << 11) + (L_ - 1 - l)) : (size_t)row;
  size_t obase = drow * (2 * DM) + (size_t)dir * DM;
  cat[obase + tid]       = f2bf(x0 * rs * w[tid]);
  cat[obase + 256 + tid] = f2bf(x1 * rs * w[tid + 256]);
}

extern "C" void kernel_launch(void* const* d_in, const int* in_sizes, int n_in,
                              void* d_out, int out_size, void* d_ws, size_t ws_size,
                              hipStream_t stream) {
  const int*   ids      = (const int*)d_in[0];
  const float* embed    = (const float*)d_in[2];
  const float* in_w     = (const float*)d_in[3];
  const float* conv_w   = (const float*)d_in[4];
  const float* conv_b   = (const float*)d_in[5];
  const float* x_w      = (const float*)d_in[6];
  const float* dt_w     = (const float*)d_in[7];
  const float* dt_bias  = (const float*)d_in[8];
  const float* A_log    = (const float*)d_in[9];
  const float* Dp       = (const float*)d_in[10];
  const float* out_w    = (const float*)d_in[11];
  const float* norm_w   = (const float*)d_in[12];
  const float* norm_f   = (const float*)d_in[13];
  const float* proj_w   = (const float*)d_in[14];
  const float* proj_b   = (const float*)d_in[15];

  char* ws = (char*)d_ws;
  size_t off = 0;
  auto alloc = [&](size_t bytes) {
    void* p = ws + off;
    off += (bytes + 255) & ~(size_t)255;
    return p;
  };
  float* res  = (float*)alloc((size_t)ROWS * DM * 4);        // 16.8 MB
  float* hid  = (float*)alloc((size_t)ROWS * DM * 4);        // 16.8 MB (x_proj partials alias)
  u16*   xnyg = (u16*)alloc((size_t)ROWS * DI * 2);          // 16.8 MB (xn | yg)
  u16*   xz   = (u16*)alloc((size_t)ROWS * 2 * DI * 2);      // 33.6 MB
  u16*   u_h  = (u16*)alloc((size_t)ROWS * DI * 2);          // 16.8 MB
  float* dtf  = (float*)alloc((size_t)ROWS * DI * 4);        // 33.6 MB
  float* chk  = (float*)alloc((size_t)2 * B_ * NCHUNK * DI * NST * 4);  // 33.6 MB
  u16*   cat  = (u16*)alloc((size_t)ROWS * 2 * DM * 2);      // 16.8 MB
  const int N_IN  = 4 * 2 * DI * DM;   // 4,194,304
  const int N_XW  = 4 * 64 * DI;       //   262,144
  const int N_OW  = 4 * DM * DI;       // 2,097,152
  const int N_PW  = DM * 2 * DM;       //   524,288
  const int N_DTW = 4 * DTR * DI;      //   131,072
  u16*   in_wb  = (u16*)alloc((size_t)N_IN * 2);             //  8.4 MB
  u16*   x_wb   = (u16*)alloc((size_t)N_XW * 2);             //  0.5 MB
  u16*   out_wb = (u16*)alloc((size_t)N_OW * 2);             //  4.2 MB
  u16*   pr_wb  = (u16*)alloc((size_t)N_PW * 2);             //  1.0 MB
  float* dtw_t  = (float*)alloc((size_t)N_DTW * 4);          //  0.5 MB
  if (off > ws_size) return;

  cvt_k<<<(N_IN / 4 + 255) / 256, 256, 0, stream>>>(in_w, in_wb, N_IN / 4);
  cvt_k<<<(N_XW / 4 + 255) / 256, 256, 0, stream>>>(x_w, x_wb, N_XW / 4);
  cvt_k<<<(N_OW / 4 + 255) / 256, 256, 0, stream>>>(out_w, out_wb, N_OW / 4);
  cvt_k<<<(N_PW / 4 + 255) / 256, 256, 0, stream>>>(proj_w, pr_wb, N_PW / 4);
  trp_k<<<N_DTW / 256, 256, 0, stream>>>(dt_w, dtw_t);

  for (int d = 0; d < 2; ++d) {
    embed_k<<<ROWS * DM / 256, 256, 0, stream>>>(ids, embed + (size_t)d * 128 * DM, res, d);
    for (int i = 0; i < 2; ++i) {
      int li = d * 2 + i;
      if (i == 0)
        addnorm_k<false><<<ROWS, 256, 0, stream>>>(res, hid, norm_w + (size_t)li * DM, xnyg);
      else
        addnorm_k<true><<<ROWS, 256, 0, stream>>>(res, hid, norm_w + (size_t)li * DM, xnyg);
      // in_proj: 256x256 tiles, grid = 32 MT x 8 NT = 256 blocks (XCD-patched)
      gemm256_k<<<256, 512, 0, stream>>>(
          xnyg, in_wb + (size_t)li * 2 * DI * DM, xz, 2 * DI, DM);
      conv_k<<<ROWS * DI / 256, 256, 0, stream>>>(
          xz, conv_w + (size_t)li * DI * 4, conv_b + (size_t)li * DI, u_h);
      // x_proj split-K x4: partials into hid (dead window until out_proj)
      gemm_bt<64, EPI_F32, 4><<<dim3(ROWS / 128, 4), 256, 0, stream>>>(
          u_h, x_wb + (size_t)li * 64 * DI, hid, nullptr, 64, DI);
      dtscan1_k<<<B_ * NCHUNK * (DI / 256), 256, 0, stream>>>(
          u_h, hid, dtw_t + (size_t)li * DTR * DI, dt_bias + (size_t)li * DI,
          A_log + (size_t)li * DI * NST, dtf, chk);
      scan2_k<<<(B_ * DI * NST) / 256, 256, 0, stream>>>(chk);
      scan3_k<<<B_ * NCHUNK * (DI / 256), 256, 0, stream>>>(
          u_h, dtf, hid, A_log + (size_t)li * DI * NST, Dp + (size_t)li * DI, chk,
          xz, xnyg);
      gemm_bt<64, EPI_F32><<<dim3(ROWS / 128, DM / 64), 256, 0, stream>>>(
          xnyg, out_wb + (size_t)li * DM * DI, hid, nullptr, DM, DI);
    }
    fincat_k<<<ROWS, 256, 0, stream>>>(hid, res, norm_f + (size_t)d * DM, cat, d);
  }
  gemm_bt<64, EPI_BIAS><<<dim3(ROWS / 128, DM / 64), 256, 0, stream>>>(
      cat, pr_wb, (float*)d_out, proj_b, DM, DI);
}

// Round 13
// 823.294 us; speedup vs baseline: 1.0236x; 1.0236x over previous
//
#include <hip/hip_runtime.h>
#include <hip/hip_bf16.h>

#define B_   4
#define L_   2048
#define DM   512
#define DI   1024
#define NST  16
#define DTR  32
#define ROWS (B_ * L_)   // 8192
#define NCHUNK 64
#define CLEN  (L_ / NCHUNK)   // 32
#define LN2R 1.4426950408889634f

typedef unsigned short u16;
typedef __attribute__((ext_vector_type(8))) short bf16x8;
typedef __attribute__((ext_vector_type(4))) float f32x4;
typedef __attribute__((ext_vector_type(4))) float float4v;
typedef __attribute__((ext_vector_type(2))) float f32x2;

__device__ __forceinline__ float bf2f(u16 h) {
  union { unsigned int u; float f; } v; v.u = ((unsigned int)h) << 16; return v.f;
}
__device__ __forceinline__ u16 f2bf(float f) {
  union { float f; unsigned int u; } v; v.f = f;
  unsigned int u = v.u;
  if ((u & 0x7fffffffu) > 0x7f800000u) return (u16)((u >> 16) | 0x0040u);
  return (u16)((u + 0x7fffu + ((u >> 16) & 1u)) >> 16);
}
__device__ __forceinline__ float sigmoidf_(float x) { return 1.f / (1.f + __expf(-x)); }

__device__ __forceinline__ f32x2 pk_mul(f32x2 a, f32x2 b) {
  f32x2 d; asm("v_pk_mul_f32 %0, %1, %2" : "=v"(d) : "v"(a), "v"(b)); return d;
}
__device__ __forceinline__ f32x2 pk_fma(f32x2 a, f32x2 b, f32x2 c) {
  f32x2 d; asm("v_pk_fma_f32 %0, %1, %2, %3" : "=v"(d) : "v"(a), "v"(b), "v"(c)); return d;
}

// async global->LDS, 16B per lane; dest = wave-uniform base + lane*16
__device__ __forceinline__ void gload16(const u16* g, u16* l) {
  __builtin_amdgcn_global_load_lds(
      (const __attribute__((address_space(1))) void*)g,
      (__attribute__((address_space(3))) void*)l, 16, 0, 0);
}

// ---------------- f32 -> bf16 weight conversion ----------------
__global__ __launch_bounds__(256) void cvt_k(const float* __restrict__ in,
                                             u16* __restrict__ out, int n4) {
  int i = blockIdx.x * 256 + threadIdx.x;
  if (i >= n4) return;
  float4v v = *(const float4v*)&in[i * 4];
  u16 o[4];
  o[0] = f2bf(v.x); o[1] = f2bf(v.y); o[2] = f2bf(v.z); o[3] = f2bf(v.w);
  *(ulong1*)&out[i * 4] = *(ulong1*)o;
}

// ---------------- dt_w transpose: [4][DI][DTR] -> [4][DTR][DI] (f32) ----------------
__global__ __launch_bounds__(256) void trp_k(const float* __restrict__ in,
                                             float* __restrict__ out) {
  int o = blockIdx.x * 256 + threadIdx.x;
  int li = o >> 15;
  int k = (o >> 10) & (DTR - 1);
  int d = o & (DI - 1);
  out[o] = in[((size_t)li * DI + d) * DTR + k];
}

// ---------------- embed gather ----------------
__global__ __launch_bounds__(256) void embed_k(const int* __restrict__ ids,
                                               const float* __restrict__ emb,
                                               float* __restrict__ res, int flip) {
  int idx = blockIdx.x * 256 + threadIdx.x;
  int c = idx & (DM - 1);
  int row = idx >> 9;
  int b = row >> 11;
  int l = row & (L_ - 1);
  int sl = flip ? (L_ - 1 - l) : l;
  int id = ids[(b << 11) + sl];
  res[idx] = emb[id * DM + c];
}

// ---------------- (res += hid); xn = rmsnorm(res) * w ----------------
template <bool ADD>
__global__ __launch_bounds__(256) void addnorm_k(float* __restrict__ res,
                                                 const float* __restrict__ hid,
                                                 const float* __restrict__ w,
                                                 u16* __restrict__ xn) {
  int row = blockIdx.x;
  int tid = threadIdx.x;
  int base = row * DM;
  float x0 = res[base + tid];
  float x1 = res[base + 256 + tid];
  if (ADD) {
    x0 += hid[base + tid];
    x1 += hid[base + 256 + tid];
    res[base + tid] = x0;
    res[base + 256 + tid] = x1;
  }
  float s = x0 * x0 + x1 * x1;
  for (int off = 32; off; off >>= 1) s += __shfl_xor(s, off);
  __shared__ float ps[4];
  if (!(tid & 63)) ps[tid >> 6] = s;
  __syncthreads();
  float tot = ps[0] + ps[1] + ps[2] + ps[3];
  float rs = 1.f / sqrtf(tot / (float)DM + 1e-5f);
  xn[base + tid]       = f2bf(x0 * rs * w[tid]);
  xn[base + 256 + tid] = f2bf(x1 * rs * w[tid + 256]);
}

// ---------------- in_proj: 256x256 tile, 8-phase fine-interleaved schedule ----------------
// Race fix vs R12: s_barrier after the prologue vmcnt (per-wave vmcnt is not a
// cross-wave landing guarantee; tile-0 phase-1 ds_reads were unordered vs other
// waves' prologue gload_lds writes).
#define MFMA_B16(a, b, c) __builtin_amdgcn_mfma_f32_16x16x32_bf16(a, b, c, 0, 0, 0)

__global__ __launch_bounds__(512) void gemm8p_k(const u16* __restrict__ A,
                                                const u16* __restrict__ W,
                                                u16* __restrict__ outp,
                                                int N, int K) {
  __shared__ u16 As[2][2][256 * 32];    // [buf][khalf][row*32+col] 64 kB
  __shared__ u16 Wsh[2][2][256 * 32];   // 64 kB
  int tid = threadIdx.x;
  int lane = tid & 63;
  int wv = tid >> 6;                    // 0..7
  int wr = wv >> 2, wc = wv & 3;        // 2M x 4N wave grid
  int bid = blockIdx.x;
  int xcd = bid & 7, jj = bid >> 3;
  int mt = (xcd & 3) * 8 + (jj & 7);    // 0..31
  int nt = (xcd >> 2) * 4 + (jj >> 3);  // 0..7
  int m0 = mt * 256, n0 = nt * 256;
  f32x4 acc[8][4];
#pragma unroll
  for (int i = 0; i < 8; ++i)
#pragma unroll
    for (int j = 0; j < 4; ++j) acc[i][j] = (f32x4){0.f, 0.f, 0.f, 0.f};
  int rr = lane & 15;
  int sl = lane >> 4;                   // logical k-slot 0..3
  int pofs = ((sl + (rr >> 1)) & 3) * 8;  // swizzled phys slot offset (elements)
  int lr = lane >> 2;                   // staging: row within 16-row group
  int ls = ((lane & 3) - (lr >> 1)) & 3;  // staging: logical slot to fetch

  auto stA = [&](int tau, int ks) {
    int buf = tau & 1;
#pragma unroll
    for (int j = 0; j < 2; ++j)
      gload16(A + (size_t)(m0 + j * 128 + wv * 16 + lr) * K + tau * 64 + ks * 32 + ls * 8,
              &As[buf][ks][(j * 128 + wv * 16) * 32]);
  };
  auto stW = [&](int tau, int ks) {
    int buf = tau & 1;
#pragma unroll
    for (int j = 0; j < 2; ++j)
      gload16(W + (size_t)(n0 + j * 128 + wv * 16 + lr) * K + tau * 64 + ks * 32 + ls * 8,
              &Wsh[buf][ks][(j * 128 + wv * 16) * 32]);
  };

  int NT = K / 64;
  // prologue: all 4 halves of tile 0
  stA(0, 0); stW(0, 0); stA(0, 1); stW(0, 1);
  asm volatile("s_waitcnt vmcnt(4)" ::: "memory");
  __builtin_amdgcn_sched_barrier(0);
  __builtin_amdgcn_s_barrier();         // cross-wave guarantee for tile-0 ks=0 data
  __builtin_amdgcn_sched_barrier(0);

  for (int tau = 0; tau < NT; ++tau) {
    int buf = tau & 1;
    bool more = (tau + 1 < NT);
    bf16x8 af[8], w0, w1;
    // ---------- phase 1: ks=0, ni 0-1 ----------
#pragma unroll
    for (int mi = 0; mi < 8; ++mi)
      af[mi] = *(bf16x8*)&As[buf][0][(wr * 128 + mi * 16 + rr) * 32 + pofs];
    w0 = *(bf16x8*)&Wsh[buf][0][(wc * 64 + 0 * 16 + rr) * 32 + pofs];
    w1 = *(bf16x8*)&Wsh[buf][0][(wc * 64 + 1 * 16 + rr) * 32 + pofs];
    if (more) stA(tau + 1, 0);
    __builtin_amdgcn_sched_barrier(0);
    __builtin_amdgcn_s_barrier();
    asm volatile("s_waitcnt lgkmcnt(0)" ::: "memory");
    __builtin_amdgcn_sched_barrier(0);
    __builtin_amdgcn_s_setprio(1);
#pragma unroll
    for (int mi = 0; mi < 8; ++mi) {
      acc[mi][0] = MFMA_B16(af[mi], w0, acc[mi][0]);
      acc[mi][1] = MFMA_B16(af[mi], w1, acc[mi][1]);
    }
    __builtin_amdgcn_s_setprio(0);
    __builtin_amdgcn_s_barrier();
    __builtin_amdgcn_sched_barrier(0);
    // ---------- phase 2: ks=0, ni 2-3 ----------
    w0 = *(bf16x8*)&Wsh[buf][0][(wc * 64 + 2 * 16 + rr) * 32 + pofs];
    w1 = *(bf16x8*)&Wsh[buf][0][(wc * 64 + 3 * 16 + rr) * 32 + pofs];
    if (more) {
      stW(tau + 1, 0);
      asm volatile("s_waitcnt vmcnt(4)" ::: "memory");   // cur-tile ks=1 halves done
    } else {
      asm volatile("s_waitcnt vmcnt(0)" ::: "memory");
    }
    __builtin_amdgcn_sched_barrier(0);
    __builtin_amdgcn_s_barrier();
    asm volatile("s_waitcnt lgkmcnt(0)" ::: "memory");
    __builtin_amdgcn_sched_barrier(0);
    __builtin_amdgcn_s_setprio(1);
#pragma unroll
    for (int mi = 0; mi < 8; ++mi) {
      acc[mi][2] = MFMA_B16(af[mi], w0, acc[mi][2]);
      acc[mi][3] = MFMA_B16(af[mi], w1, acc[mi][3]);
    }
    __builtin_amdgcn_s_setprio(0);
    __builtin_amdgcn_s_barrier();
    __builtin_amdgcn_sched_barrier(0);
    // ---------- phase 3: ks=1, ni 0-1 ----------
#pragma unroll
    for (int mi = 0; mi < 8; ++mi)
      af[mi] = *(bf16x8*)&As[buf][1][(wr * 128 + mi * 16 + rr) * 32 + pofs];
    w0 = *(bf16x8*)&Wsh[buf][1][(wc * 64 + 0 * 16 + rr) * 32 + pofs];
    w1 = *(bf16x8*)&Wsh[buf][1][(wc * 64 + 1 * 16 + rr) * 32 + pofs];
    if (more) stA(tau + 1, 1);
    __builtin_amdgcn_sched_barrier(0);
    __builtin_amdgcn_s_barrier();
    asm volatile("s_waitcnt lgkmcnt(0)" ::: "memory");
    __builtin_amdgcn_sched_barrier(0);
    __builtin_amdgcn_s_setprio(1);
#pragma unroll
    for (int mi = 0; mi < 8; ++mi) {
      acc[mi][0] = MFMA_B16(af[mi], w0, acc[mi][0]);
      acc[mi][1] = MFMA_B16(af[mi], w1, acc[mi][1]);
    }
    __builtin_amdgcn_s_setprio(0);
    __builtin_amdgcn_s_barrier();
    __builtin_amdgcn_sched_barrier(0);
    // ---------- phase 4: ks=1, ni 2-3 ----------
    w0 = *(bf16x8*)&Wsh[buf][1][(wc * 64 + 2 * 16 + rr) * 32 + pofs];
    w1 = *(bf16x8*)&Wsh[buf][1][(wc * 64 + 3 * 16 + rr) * 32 + pofs];
    if (more) {
      stW(tau + 1, 1);
      asm volatile("s_waitcnt vmcnt(4)" ::: "memory");   // next-tile ks=0 halves done
    }
    __builtin_amdgcn_sched_barrier(0);
    __builtin_amdgcn_s_barrier();
    asm volatile("s_waitcnt lgkmcnt(0)" ::: "memory");
    __builtin_amdgcn_sched_barrier(0);
    __builtin_amdgcn_s_setprio(1);
#pragma unroll
    for (int mi = 0; mi < 8; ++mi) {
      acc[mi][2] = MFMA_B16(af[mi], w0, acc[mi][2]);
      acc[mi][3] = MFMA_B16(af[mi], w1, acc[mi][3]);
    }
    __builtin_amdgcn_s_setprio(0);
    __builtin_amdgcn_s_barrier();
    __builtin_amdgcn_sched_barrier(0);
  }
  // epilogue: C/D layout col = lane&15, row = (lane>>4)*4 + j
  int cr = (lane >> 4) << 2;
  int cc = lane & 15;
#pragma unroll
  for (int mi = 0; mi < 8; ++mi)
#pragma unroll
    for (int ni = 0; ni < 4; ++ni) {
      int row = m0 + wr * 128 + mi * 16 + cr;
      int col = n0 + wc * 64 + ni * 16 + cc;
#pragma unroll
      for (int j = 0; j < 4; ++j)
        outp[(size_t)(row + j) * N + col] = f2bf(acc[mi][ni][j]);
    }
}

// ---------------- GEMM (generic): 4-buffer ring, stage-ahead-3, one barrier/step ----------------
#define EPI_F32  0
#define EPI_BF16 1
#define EPI_BIAS 2

template <int BN, int EPI, int SK = 1>
__global__ __launch_bounds__(256) void gemm_bt(const u16* __restrict__ A,
                                               const u16* __restrict__ W,
                                               void* __restrict__ outp,
                                               const float* __restrict__ bias,
                                               int N, int K) {
  constexpr int BM = 128, BK = 32;
  constexpr int NF = BN / 32;
  constexpr int G = (BN == 128) ? 4 : 3;
  __shared__ u16 As[4][BM * BK];
  __shared__ u16 Wsh[4][BN * BK];
  int tid = threadIdx.x;
  int lane = tid & 63;
  int wv = tid >> 6;
  int wr = wv >> 1, wc = wv & 1;
  int m0 = blockIdx.x * BM;
  int n0 = (SK > 1) ? 0 : blockIdx.y * BN;
  int koff = (SK > 1) ? blockIdx.y * (K / SK) : 0;
  int KS = K / SK;
  int NK = KS / BK;
  f32x4 acc[4][NF];
#pragma unroll
  for (int i = 0; i < 4; ++i)
#pragma unroll
    for (int j = 0; j < NF; ++j) acc[i][j] = (f32x4){0.f, 0.f, 0.f, 0.f};
  int rr = lane & 15;
  int kk = (lane >> 4) << 3;
  int l4 = lane >> 2;
  int c8 = (lane & 3) << 3;
  const u16* Ag = A + (size_t)(m0 + l4) * K + koff + c8;
  const u16* Wg = W + (size_t)(n0 + l4) * K + koff + c8;

  auto stage = [&](int k0, int buf) {
    gload16(Ag + (size_t)(wv * 16) * K + k0, &As[buf][wv * 512]);
    gload16(Ag + (size_t)((wv + 4) * 16) * K + k0, &As[buf][(wv + 4) * 512]);
    gload16(Wg + (size_t)(wv * 16) * K + k0, &Wsh[buf][wv * 512]);
    if (BN == 128)
      gload16(Wg + (size_t)((wv + 4) * 16) * K + k0, &Wsh[buf][(wv + 4) * 512]);
  };

  stage(0, 0); stage(BK, 1); stage(2 * BK, 2);
  for (int k = 0; k < NK; ++k) {
    if (k < NK - 2)
      asm volatile("s_waitcnt vmcnt(%0)" :: "n"(2 * G) : "memory");
    else if (k == NK - 2)
      asm volatile("s_waitcnt vmcnt(%0)" :: "n"(G) : "memory");
    else
      asm volatile("s_waitcnt vmcnt(0)" ::: "memory");
    __builtin_amdgcn_s_barrier();
    __builtin_amdgcn_sched_barrier(0);
    if (k + 3 < NK) stage((k + 3) * BK, (k + 3) & 3);
    __builtin_amdgcn_sched_barrier(0);
    int cur = k & 3;
    bf16x8 af[4], wf[NF];
#pragma unroll
    for (int mi = 0; mi < 4; ++mi)
      af[mi] = *(bf16x8*)&As[cur][(wr * 64 + mi * 16 + rr) * BK + kk];
#pragma unroll
    for (int ni = 0; ni < NF; ++ni)
      wf[ni] = *(bf16x8*)&Wsh[cur][(wc * (BN / 2) + ni * 16 + rr) * BK + kk];
#pragma unroll
    for (int mi = 0; mi < 4; ++mi)
#pragma unroll
      for (int ni = 0; ni < NF; ++ni)
        acc[mi][ni] = __builtin_amdgcn_mfma_f32_16x16x32_bf16(af[mi], wf[ni], acc[mi][ni], 0, 0, 0);
  }
  int cr = (lane >> 4) << 2;
  int cc = lane & 15;
  float* outF = (float*)outp + ((SK > 1) ? (size_t)blockIdx.y * (size_t)ROWS * N : 0);
#pragma unroll
  for (int mi = 0; mi < 4; ++mi)
#pragma unroll
    for (int ni = 0; ni < NF; ++ni) {
      int row = m0 + wr * 64 + mi * 16 + cr;
      int col = n0 + wc * (BN / 2) + ni * 16 + cc;
      float bv = (EPI == EPI_BIAS) ? bias[col] : 0.f;
#pragma unroll
      for (int j = 0; j < 4; ++j) {
        float v = acc[mi][ni][j] + bv;
        if (EPI == EPI_BF16)
          ((u16*)outp)[(size_t)(row + j) * N + col] = f2bf(v);
        else
          outF[(size_t)(row + j) * N + col] = v;
      }
    }
}

// ---------------- depthwise causal conv (k=4) + bias + SiLU (bf16 out) ----------------
__global__ __launch_bounds__(256) void conv_k(const u16* __restrict__ xz,
                                              const float* __restrict__ cw,
                                              const float* __restrict__ cb,
                                              u16* __restrict__ uh) {
  int idx = blockIdx.x * 256 + threadIdx.x;
  int c = idx & (DI - 1);
  int row = idx >> 10;
  int l = row & (L_ - 1);
  float acc = cb[c];
#pragma unroll
  for (int j = 0; j < 4; ++j) {
    int ls = l + j - 3;
    if (ls >= 0)
      acc += bf2f(xz[(size_t)(row + j - 3) * (2 * DI) + c]) * cw[c * 4 + j];
  }
  float s = acc * sigmoidf_(acc);
  uh[idx] = f2bf(s);
}

// A-structure check: A[n] == (n+1)*A[0]
__device__ __forceinline__ bool a_fast(const float* alog, int d, float& a20) {
  a20 = -__expf(alog[d * NST]) * LN2R;
  bool fast = true;
#pragma unroll
  for (int n = 1; n < NST; ++n) {
    float an = -__expf(alog[d * NST + n]) * LN2R;
    fast &= (fabsf(an - (float)(n + 1) * a20) <= 1e-5f * (float)(n + 1) * fabsf(a20));
  }
  return fast;
}

// stage xs[32][64] by summing 4 x_proj split-K partials
__device__ __forceinline__ void stage_xs(float (*xs)[64], const float* xp,
                                         int b, int t0, int tid) {
  size_t base = ((size_t)b * L_ + t0) * 64;
  const float4v* s0 = (const float4v*)(xp + base);
  const float4v* s1 = (const float4v*)(xp + (size_t)ROWS * 64 + base);
  const float4v* s2 = (const float4v*)(xp + (size_t)2 * ROWS * 64 + base);
  const float4v* s3 = (const float4v*)(xp + (size_t)3 * ROWS * 64 + base);
  float4v* dst = (float4v*)&xs[0][0];
  dst[tid]       = s0[tid]       + s1[tid]       + s2[tid]       + s3[tid];
  dst[tid + 256] = s0[tid + 256] + s1[tid + 256] + s2[tid + 256] + s3[tid + 256];
}

// ---------------- fused dt-projection + scan pass 1 ----------------
__global__ __launch_bounds__(256) void dtscan1_k(const u16* __restrict__ uh,
                                                 const float* __restrict__ xp,
                                                 const float* __restrict__ dtw_t,
                                                 const float* __restrict__ dtb,
                                                 const float* __restrict__ alog,
                                                 float* __restrict__ dtf,
                                                 float* __restrict__ chk) {
  __shared__ float xs[CLEN][64];
  int blk = blockIdx.x;
  int db = blk & 3;
  int c  = (blk >> 2) & (NCHUNK - 1);
  int b  = blk >> 8;
  int tid = threadIdx.x;
  int d  = db * 256 + tid;
  int t0 = c * CLEN;
  stage_xs(xs, xp, b, t0, tid);
  f32x2 w2[16];
#pragma unroll
  for (int j = 0; j < 16; ++j)
    w2[j] = (f32x2){dtw_t[(size_t)(2 * j) * DI + d], dtw_t[(size_t)(2 * j + 1) * DI + d]};
  float bias = dtb[d];
  float a20;
  bool fast = a_fast(alog, d, a20);
  __syncthreads();
  float S = 0.f;
  size_t ubase = ((size_t)b * L_ + t0) * DI + d;
  f32x2 h2[8];
#pragma unroll
  for (int q = 0; q < 8; ++q) h2[q] = (f32x2){0.f, 0.f};
  for (int t = 0; t < CLEN; ++t) {
    f32x2 a2 = {bias, 0.f};
    const f32x2* xr2 = (const f32x2*)&xs[t][0];
#pragma unroll
    for (int j = 0; j < 16; ++j) a2 = pk_fma(xr2[j], w2[j], a2);
    float a = a2.x + a2.y;
    float dtv = (a > 15.f) ? a : __logf(1.f + __expf(a));
    dtf[ubase] = dtv;
    float du = dtv * bf2f(uh[ubase]);
    S += dtv;
    if (fast) {
      float p1 = exp2f(dtv * a20);
      float p2 = p1 * p1;
      f32x2 pw = {p1, p2};
      f32x2 pst = {p2, p2};
      f32x2 du2 = {du, du};
#pragma unroll
      for (int k = 0; k < 4; ++k) {
        f32x4 bv = *(const f32x4*)&xs[t][DTR + k * 4];
        f32x2 blo = __builtin_shufflevector(bv, bv, 0, 1);
        f32x2 bhi = __builtin_shufflevector(bv, bv, 2, 3);
        h2[2 * k]     = pk_fma(pw, h2[2 * k], pk_mul(du2, blo));
        pw = pk_mul(pw, pst);
        h2[2 * k + 1] = pk_fma(pw, h2[2 * k + 1], pk_mul(du2, bhi));
        if (k < 3) pw = pk_mul(pw, pst);
      }
    } else {
#pragma unroll
      for (int q = 0; q < 8; ++q) {
        float e0 = exp2f(dtv * -__expf(alog[d * NST + 2 * q]) * LN2R);
        float e1 = exp2f(dtv * -__expf(alog[d * NST + 2 * q + 1]) * LN2R);
        f32x2 bv = *(const f32x2*)&xs[t][DTR + q * 2];
        h2[q] = pk_fma((f32x2){e0, e1}, h2[q], pk_mul((f32x2){du, du}, bv));
      }
    }
    ubase += DI;
  }
  const size_t H = (size_t)B_ * NCHUNK * DI * NST;
  size_t idx = ((size_t)(b * NCHUNK + c) * DI + d) * NST;
#pragma unroll
  for (int n = 0; n < NST; ++n) {
    float an = -__expf(alog[d * NST + n]) * LN2R;
    chk[idx + n]     = exp2f(an * S);
    chk[H + idx + n] = (n & 1) ? h2[n >> 1].y : h2[n >> 1].x;
  }
}

// pass 2
__global__ __launch_bounds__(256) void scan2_k(float* __restrict__ chk) {
  int j = blockIdx.x * 256 + threadIdx.x;
  int n = j & 15;
  int d = (j >> 4) & (DI - 1);
  int b = j >> 14;
  const size_t H = (size_t)B_ * NCHUNK * DI * NST;
  float h = 0.f;
  for (int c = 0; c < NCHUNK; ++c) {
    size_t idx = ((size_t)(b * NCHUNK + c) * DI + d) * NST + n;
    float a = chk[idx];
    float hl = chk[H + idx];
    chk[H + idx] = h;
    h = a * h + hl;
  }
}

// pass 3
__global__ __launch_bounds__(256) void scan3_k(const u16* __restrict__ uh,
                                               const float* __restrict__ dtf,
                                               const float* __restrict__ xp,
                                               const float* __restrict__ alog,
                                               const float* __restrict__ dvec,
                                               const float* __restrict__ chk,
                                               const u16* __restrict__ xz,
                                               u16* __restrict__ yg) {
  __shared__ float xs[CLEN][64];
  int blk = blockIdx.x;
  int db = blk & 3;
  int c  = (blk >> 2) & (NCHUNK - 1);
  int b  = blk >> 8;
  int tid = threadIdx.x;
  int d  = db * 256 + tid;
  int t0 = c * CLEN;
  stage_xs(xs, xp, b, t0, tid);
  float a20;
  bool fast = a_fast(alog, d, a20);
  const size_t H = (size_t)B_ * NCHUNK * DI * NST;
  size_t cidx = ((size_t)(b * NCHUNK + c) * DI + d) * NST;
  f32x2 h2[8];
#pragma unroll
  for (int q = 0; q < 8; ++q) h2[q] = *(const f32x2*)&chk[H + cidx + 2 * q];
  float Dv = dvec[d];
  __syncthreads();
  size_t ubase = ((size_t)b * L_ + t0) * DI + d;
  size_t zbase = ((size_t)b * L_ + t0) * (2 * DI) + DI + d;
  if (fast) {
    for (int t = 0; t < CLEN; ++t) {
      float dtv = dtf[ubase];
      float uv  = bf2f(uh[ubase]);
      float du  = dtv * uv;
      float p1 = exp2f(dtv * a20);
      float p2 = p1 * p1;
      f32x2 pw = {p1, p2};
      f32x2 pst = {p2, p2};
      f32x2 du2 = {du, du};
      f32x2 acc2 = {0.f, 0.f};
#pragma unroll
      for (int k = 0; k < 4; ++k) {
        f32x4 bv = *(const f32x4*)&xs[t][DTR + k * 4];
        f32x4 cv = *(const f32x4*)&xs[t][DTR + NST + k * 4];
        f32x2 blo = __builtin_shufflevector(bv, bv, 0, 1);
        f32x2 bhi = __builtin_shufflevector(bv, bv, 2, 3);
        f32x2 clo = __builtin_shufflevector(cv, cv, 0, 1);
        f32x2 chi = __builtin_shufflevector(cv, cv, 2, 3);
        h2[2 * k]     = pk_fma(pw, h2[2 * k], pk_mul(du2, blo));
        acc2          = pk_fma(h2[2 * k], clo, acc2);
        pw = pk_mul(pw, pst);
        h2[2 * k + 1] = pk_fma(pw, h2[2 * k + 1], pk_mul(du2, bhi));
        acc2          = pk_fma(h2[2 * k + 1], chi, acc2);
        if (k < 3) pw = pk_mul(pw, pst);
      }
      float y = acc2.x + acc2.y + uv * Dv;
      float z = bf2f(xz[zbase]);
      yg[ubase] = f2bf(y * z * sigmoidf_(z));
      ubase += DI; zbase += 2 * DI;
    }
  } else {
    float A2[NST];
#pragma unroll
    for (int n = 0; n < NST; ++n) A2[n] = -__expf(alog[d * NST + n]) * LN2R;
    for (int t = 0; t < CLEN; ++t) {
      float dtv = dtf[ubase];
      float uv  = bf2f(uh[ubase]);
      float du  = dtv * uv;
      f32x2 acc2 = {0.f, 0.f};
#pragma unroll
      for (int q = 0; q < 8; ++q) {
        f32x2 bv = *(const f32x2*)&xs[t][DTR + q * 2];
        f32x2 cv = *(const f32x2*)&xs[t][DTR + NST + q * 2];
        f32x2 e = {exp2f(dtv * A2[2 * q]), exp2f(dtv * A2[2 * q + 1])};
        h2[q] = pk_fma(e, h2[q], pk_mul((f32x2){du, du}, bv));
        acc2 = pk_fma(h2[q], cv, acc2);
      }
      float y = acc2.x + acc2.y + uv * Dv;
      float z = bf2f(xz[zbase]);
      yg[ubase] = f2bf(y * z * sigmoidf_(z));
      ubase += DI; zbase += 2 * DI;
    }
  }
}

// ---------------- final rmsnorm(hid+res) -> concat buffer ----------------
__global__ __launch_bounds__(256) void fincat_k(const float* __restrict__ hid,
                                                const float* __restrict__ res,
                                                const float* __restrict__ w,
                                                u16* __restrict__ cat, int dir) {
  int row = blockIdx.x;
  int tid = threadIdx.x;
  int base = row * DM;
  float x0 = hid[base + tid] + res[base + tid];
  float x1 = hid[base + 256 + tid] + res[base + 256 + tid];
  float s = x0 * x0 + x1 * x1;
  for (int off = 32; off; off >>= 1) s += __shfl_xor(s, off);
  __shared__ float ps[4];
  if (!(tid & 63)) ps[tid >> 6] = s;
  __syncthreads();
  float tot = ps[0] + ps[1] + ps[2] + ps[3];
  float rs = 1.f / sqrtf(tot / (float)DM + 1e-5f);
  int b = row >> 11, l = row & (L_ - 1);
  size_t drow = dir ? ((size_t)(b << 11) + (L_ - 1 - l)) : (size_t)row;
  size_t obase = drow * (2 * DM) + (size_t)dir * DM;
  cat[obase + tid]       = f2bf(x0 * rs * w[tid]);
  cat[obase + 256 + tid] = f2bf(x1 * rs * w[tid + 256]);
}

extern "C" void kernel_launch(void* const* d_in, const int* in_sizes, int n_in,
                              void* d_out, int out_size, void* d_ws, size_t ws_size,
                              hipStream_t stream) {
  const int*   ids      = (const int*)d_in[0];
  const float* embed    = (const float*)d_in[2];
  const float* in_w     = (const float*)d_in[3];
  const float* conv_w   = (const float*)d_in[4];
  const float* conv_b   = (const float*)d_in[5];
  const float* x_w      = (const float*)d_in[6];
  const float* dt_w     = (const float*)d_in[7];
  const float* dt_bias  = (const float*)d_in[8];
  const float* A_log    = (const float*)d_in[9];
  const float* Dp       = (const float*)d_in[10];
  const float* out_w    = (const float*)d_in[11];
  const float* norm_w   = (const float*)d_in[12];
  const float* norm_f   = (const float*)d_in[13];
  const float* proj_w   = (const float*)d_in[14];
  const float* proj_b   = (const float*)d_in[15];

  char* ws = (char*)d_ws;
  size_t off = 0;
  auto alloc = [&](size_t bytes) {
    void* p = ws + off;
    off += (bytes + 255) & ~(size_t)255;
    return p;
  };
  float* res  = (float*)alloc((size_t)ROWS * DM * 4);
  float* hid  = (float*)alloc((size_t)ROWS * DM * 4);
  u16*   xnyg = (u16*)alloc((size_t)ROWS * DI * 2);
  u16*   xz   = (u16*)alloc((size_t)ROWS * 2 * DI * 2);
  u16*   u_h  = (u16*)alloc((size_t)ROWS * DI * 2);
  float* dtf  = (float*)alloc((size_t)ROWS * DI * 4);
  float* chk  = (float*)alloc((size_t)2 * B_ * NCHUNK * DI * NST * 4);
  u16*   cat  = (u16*)alloc((size_t)ROWS * 2 * DM * 2);
  const int N_IN  = 4 * 2 * DI * DM;
  const int N_XW  = 4 * 64 * DI;
  const int N_OW  = 4 * DM * DI;
  const int N_PW  = DM * 2 * DM;
  const int N_DTW = 4 * DTR * DI;
  u16*   in_wb  = (u16*)alloc((size_t)N_IN * 2);
  u16*   x_wb   = (u16*)alloc((size_t)N_XW * 2);
  u16*   out_wb = (u16*)alloc((size_t)N_OW * 2);
  u16*   pr_wb  = (u16*)alloc((size_t)N_PW * 2);
  float* dtw_t  = (float*)alloc((size_t)N_DTW * 4);
  if (off > ws_size) return;

  cvt_k<<<(N_IN / 4 + 255) / 256, 256, 0, stream>>>(in_w, in_wb, N_IN / 4);
  cvt_k<<<(N_XW / 4 + 255) / 256, 256, 0, stream>>>(x_w, x_wb, N_XW / 4);
  cvt_k<<<(N_OW / 4 + 255) / 256, 256, 0, stream>>>(out_w, out_wb, N_OW / 4);
  cvt_k<<<(N_PW / 4 + 255) / 256, 256, 0, stream>>>(proj_w, pr_wb, N_PW / 4);
  trp_k<<<N_DTW / 256, 256, 0, stream>>>(dt_w, dtw_t);

  for (int d = 0; d < 2; ++d) {
    embed_k<<<ROWS * DM / 256, 256, 0, stream>>>(ids, embed + (size_t)d * 128 * DM, res, d);
    for (int i = 0; i < 2; ++i) {
      int li = d * 2 + i;
      if (i == 0)
        addnorm_k<false><<<ROWS, 256, 0, stream>>>(res, hid, norm_w + (size_t)li * DM, xnyg);
      else
        addnorm_k<true><<<ROWS, 256, 0, stream>>>(res, hid, norm_w + (size_t)li * DM, xnyg);
      gemm8p_k<<<256, 512, 0, stream>>>(
          xnyg, in_wb + (size_t)li * 2 * DI * DM, xz, 2 * DI, DM);
      conv_k<<<ROWS * DI / 256, 256, 0, stream>>>(
          xz, conv_w + (size_t)li * DI * 4, conv_b + (size_t)li * DI, u_h);
      gemm_bt<64, EPI_F32, 4><<<dim3(ROWS / 128, 4), 256, 0, stream>>>(
          u_h, x_wb + (size_t)li * 64 * DI, hid, nullptr, 64, DI);
      dtscan1_k<<<B_ * NCHUNK * (DI / 256), 256, 0, stream>>>(
          u_h, hid, dtw_t + (size_t)li * DTR * DI, dt_bias + (size_t)li * DI,
          A_log + (size_t)li * DI * NST, dtf, chk);
      scan2_k<<<(B_ * DI * NST) / 256, 256, 0, stream>>>(chk);
      scan3_k<<<B_ * NCHUNK * (DI / 256), 256, 0, stream>>>(
          u_h, dtf, hid, A_log + (size_t)li * DI * NST, Dp + (size_t)li * DI, chk,
          xz, xnyg);
      gemm_bt<64, EPI_F32><<<dim3(ROWS / 128, DM / 64), 256, 0, stream>>>(
          xnyg, out_wb + (size_t)li * DM * DI, hid, nullptr, DM, DI);
    }
    fincat_k<<<ROWS, 256, 0, stream>>>(hid, res, norm_f + (size_t)d * DM, cat, d);
  }
  gemm_bt<64, EPI_BIAS><<<dim3(ROWS / 128, DM / 64), 256, 0, stream>>>(
      cat, pr_wb, (float*)d_out, proj_b, DM, DI);
}

// Round 14
// 775.318 us; speedup vs baseline: 1.0870x; 1.0619x over previous
//
#include <hip/hip_runtime.h>
#include <hip/hip_bf16.h>

#define B_   4
#define L_   2048
#define DM   512
#define DI   1024
#define NST  16
#define DTR  32
#define ROWS  (B_ * L_)        // 8192
#define ROWS2 (2 * ROWS)       // 16384 (both directions)
#define NCHUNK 32
#define CLEN  (L_ / NCHUNK)    // 64
#define LN2R 1.4426950408889634f

typedef unsigned short u16;
typedef __attribute__((ext_vector_type(8))) short bf16x8;
typedef __attribute__((ext_vector_type(4))) float f32x4;
typedef __attribute__((ext_vector_type(4))) float float4v;
typedef __attribute__((ext_vector_type(2))) float f32x2;

__device__ __forceinline__ float bf2f(u16 h) {
  union { unsigned int u; float f; } v; v.u = ((unsigned int)h) << 16; return v.f;
}
__device__ __forceinline__ u16 f2bf(float f) {
  union { float f; unsigned int u; } v; v.f = f;
  unsigned int u = v.u;
  if ((u & 0x7fffffffu) > 0x7f800000u) return (u16)((u >> 16) | 0x0040u);
  return (u16)((u + 0x7fffu + ((u >> 16) & 1u)) >> 16);
}
__device__ __forceinline__ float sigmoidf_(float x) { return 1.f / (1.f + __expf(-x)); }

__device__ __forceinline__ f32x2 pk_mul(f32x2 a, f32x2 b) {
  f32x2 d; asm("v_pk_mul_f32 %0, %1, %2" : "=v"(d) : "v"(a), "v"(b)); return d;
}
__device__ __forceinline__ f32x2 pk_fma(f32x2 a, f32x2 b, f32x2 c) {
  f32x2 d; asm("v_pk_fma_f32 %0, %1, %2, %3" : "=v"(d) : "v"(a), "v"(b), "v"(c)); return d;
}

__device__ __forceinline__ void gload16(const u16* g, u16* l) {
  __builtin_amdgcn_global_load_lds(
      (const __attribute__((address_space(1))) void*)g,
      (__attribute__((address_space(3))) void*)l, 16, 0, 0);
}

// ---------------- f32 -> bf16 weight conversion ----------------
__global__ __launch_bounds__(256) void cvt_k(const float* __restrict__ in,
                                             u16* __restrict__ out, int n4) {
  int i = blockIdx.x * 256 + threadIdx.x;
  if (i >= n4) return;
  float4v v = *(const float4v*)&in[i * 4];
  u16 o[4];
  o[0] = f2bf(v.x); o[1] = f2bf(v.y); o[2] = f2bf(v.z); o[3] = f2bf(v.w);
  *(ulong1*)&out[i * 4] = *(ulong1*)o;
}

// ---------------- dt_w transpose: [4][DI][DTR] -> [4][DTR][DI] (f32) ----------------
__global__ __launch_bounds__(256) void trp_k(const float* __restrict__ in,
                                             float* __restrict__ out) {
  int o = blockIdx.x * 256 + threadIdx.x;
  int li = o >> 15;
  int k = (o >> 10) & (DTR - 1);
  int d = o & (DI - 1);
  out[o] = in[((size_t)li * DI + d) * DTR + k];
}

// ---------------- embed gather, both directions ----------------
__global__ __launch_bounds__(256) void embed_k(const int* __restrict__ ids,
                                               const float* __restrict__ emb,
                                               float* __restrict__ res) {
  int idx = blockIdx.x * 256 + threadIdx.x;   // ROWS2*DM
  int c = idx & (DM - 1);
  int row = idx >> 9;                          // 0..16383
  int dir = row >> 13;
  int r = row & (ROWS - 1);
  int b = r >> 11;
  int l = r & (L_ - 1);
  int sl = dir ? (L_ - 1 - l) : l;
  int id = ids[(b << 11) + sl];
  res[idx] = emb[(size_t)dir * 128 * DM + id * DM + c];
}

// ---------------- (res += hid); xn = rmsnorm(res) * w (per-dir weights) ----------------
template <bool ADD>
__global__ __launch_bounds__(256) void addnorm_k(float* __restrict__ res,
                                                 const float* __restrict__ hid,
                                                 const float* __restrict__ norm_w,
                                                 int layer,
                                                 u16* __restrict__ xn) {
  int row = blockIdx.x;                        // 0..16383
  int dir = row >> 13;
  const float* w = norm_w + (size_t)(dir * 2 + layer) * DM;
  int tid = threadIdx.x;
  int base = row * DM;
  float x0 = res[base + tid];
  float x1 = res[base + 256 + tid];
  if (ADD) {
    x0 += hid[base + tid];
    x1 += hid[base + 256 + tid];
    res[base + tid] = x0;
    res[base + 256 + tid] = x1;
  }
  float s = x0 * x0 + x1 * x1;
  for (int off = 32; off; off >>= 1) s += __shfl_xor(s, off);
  __shared__ float ps[4];
  if (!(tid & 63)) ps[tid >> 6] = s;
  __syncthreads();
  float tot = ps[0] + ps[1] + ps[2] + ps[3];
  float rs = 1.f / sqrtf(tot / (float)DM + 1e-5f);
  xn[base + tid]       = f2bf(x0 * rs * w[tid]);
  xn[base + 256 + tid] = f2bf(x1 * rs * w[tid + 256]);
}

// ---------------- in_proj: 256x256 tile, 8-phase schedule, M=16384 both dirs ----------------
#define MFMA_B16(a, b, c) __builtin_amdgcn_mfma_f32_16x16x32_bf16(a, b, c, 0, 0, 0)

__global__ __launch_bounds__(512) void gemm8p_k(const u16* __restrict__ A,
                                                const u16* __restrict__ W,   // layer-i base (dir0)
                                                u16* __restrict__ outU,      // [row][DI] u-half
                                                u16* __restrict__ outZ,      // [row][DI] z-half
                                                int K) {
  __shared__ u16 As[2][2][256 * 32];    // 64 kB
  __shared__ u16 Wsh[2][2][256 * 32];   // 64 kB
  int tid = threadIdx.x;
  int lane = tid & 63;
  int wv = tid >> 6;
  int wr = wv >> 2, wc = wv & 3;        // 2M x 4N waves
  int bid = blockIdx.x;                 // 512 blocks: 64 mt x 8 nt
  int xcd = bid & 7, jj = bid >> 3;
  int mt = xcd * 8 + (jj & 7);          // 0..63 (each XCD: 8 contiguous mt)
  int nt = jj >> 3;                     // 0..7
  int m0 = mt * 256, n0 = nt * 256;
  const u16* Weff = W + (size_t)(m0 >> 13) * (size_t)2 * (2 * DI) * DM;  // dir stride = 2 layers
  f32x4 acc[8][4];
#pragma unroll
  for (int i = 0; i < 8; ++i)
#pragma unroll
    for (int j = 0; j < 4; ++j) acc[i][j] = (f32x4){0.f, 0.f, 0.f, 0.f};
  int rr = lane & 15;
  int sl = lane >> 4;
  int pofs = ((sl + (rr >> 1)) & 3) * 8;
  int lr = lane >> 2;
  int ls = ((lane & 3) - (lr >> 1)) & 3;

  auto stA = [&](int tau, int ks) {
    int buf = tau & 1;
#pragma unroll
    for (int j = 0; j < 2; ++j)
      gload16(A + (size_t)(m0 + j * 128 + wv * 16 + lr) * K + tau * 64 + ks * 32 + ls * 8,
              &As[buf][ks][(j * 128 + wv * 16) * 32]);
  };
  auto stW = [&](int tau, int ks) {
    int buf = tau & 1;
#pragma unroll
    for (int j = 0; j < 2; ++j)
      gload16(Weff + (size_t)(n0 + j * 128 + wv * 16 + lr) * K + tau * 64 + ks * 32 + ls * 8,
              &Wsh[buf][ks][(j * 128 + wv * 16) * 32]);
  };

  int NT = K / 64;
  stA(0, 0); stW(0, 0); stA(0, 1); stW(0, 1);
  asm volatile("s_waitcnt vmcnt(4)" ::: "memory");
  __builtin_amdgcn_sched_barrier(0);
  __builtin_amdgcn_s_barrier();
  __builtin_amdgcn_sched_barrier(0);

  for (int tau = 0; tau < NT; ++tau) {
    int buf = tau & 1;
    bool more = (tau + 1 < NT);
    bf16x8 af[8], w0, w1;
    // phase 1: ks=0, ni 0-1
#pragma unroll
    for (int mi = 0; mi < 8; ++mi)
      af[mi] = *(bf16x8*)&As[buf][0][(wr * 128 + mi * 16 + rr) * 32 + pofs];
    w0 = *(bf16x8*)&Wsh[buf][0][(wc * 64 + 0 * 16 + rr) * 32 + pofs];
    w1 = *(bf16x8*)&Wsh[buf][0][(wc * 64 + 1 * 16 + rr) * 32 + pofs];
    if (more) stA(tau + 1, 0);
    __builtin_amdgcn_sched_barrier(0);
    __builtin_amdgcn_s_barrier();
    asm volatile("s_waitcnt lgkmcnt(0)" ::: "memory");
    __builtin_amdgcn_sched_barrier(0);
    __builtin_amdgcn_s_setprio(1);
#pragma unroll
    for (int mi = 0; mi < 8; ++mi) {
      acc[mi][0] = MFMA_B16(af[mi], w0, acc[mi][0]);
      acc[mi][1] = MFMA_B16(af[mi], w1, acc[mi][1]);
    }
    __builtin_amdgcn_s_setprio(0);
    __builtin_amdgcn_s_barrier();
    __builtin_amdgcn_sched_barrier(0);
    // phase 2: ks=0, ni 2-3
    w0 = *(bf16x8*)&Wsh[buf][0][(wc * 64 + 2 * 16 + rr) * 32 + pofs];
    w1 = *(bf16x8*)&Wsh[buf][0][(wc * 64 + 3 * 16 + rr) * 32 + pofs];
    if (more) {
      stW(tau + 1, 0);
      asm volatile("s_waitcnt vmcnt(4)" ::: "memory");
    } else {
      asm volatile("s_waitcnt vmcnt(0)" ::: "memory");
    }
    __builtin_amdgcn_sched_barrier(0);
    __builtin_amdgcn_s_barrier();
    asm volatile("s_waitcnt lgkmcnt(0)" ::: "memory");
    __builtin_amdgcn_sched_barrier(0);
    __builtin_amdgcn_s_setprio(1);
#pragma unroll
    for (int mi = 0; mi < 8; ++mi) {
      acc[mi][2] = MFMA_B16(af[mi], w0, acc[mi][2]);
      acc[mi][3] = MFMA_B16(af[mi], w1, acc[mi][3]);
    }
    __builtin_amdgcn_s_setprio(0);
    __builtin_amdgcn_s_barrier();
    __builtin_amdgcn_sched_barrier(0);
    // phase 3: ks=1, ni 0-1
#pragma unroll
    for (int mi = 0; mi < 8; ++mi)
      af[mi] = *(bf16x8*)&As[buf][1][(wr * 128 + mi * 16 + rr) * 32 + pofs];
    w0 = *(bf16x8*)&Wsh[buf][1][(wc * 64 + 0 * 16 + rr) * 32 + pofs];
    w1 = *(bf16x8*)&Wsh[buf][1][(wc * 64 + 1 * 16 + rr) * 32 + pofs];
    if (more) stA(tau + 1, 1);
    __builtin_amdgcn_sched_barrier(0);
    __builtin_amdgcn_s_barrier();
    asm volatile("s_waitcnt lgkmcnt(0)" ::: "memory");
    __builtin_amdgcn_sched_barrier(0);
    __builtin_amdgcn_s_setprio(1);
#pragma unroll
    for (int mi = 0; mi < 8; ++mi) {
      acc[mi][0] = MFMA_B16(af[mi], w0, acc[mi][0]);
      acc[mi][1] = MFMA_B16(af[mi], w1, acc[mi][1]);
    }
    __builtin_amdgcn_s_setprio(0);
    __builtin_amdgcn_s_barrier();
    __builtin_amdgcn_sched_barrier(0);
    // phase 4: ks=1, ni 2-3
    w0 = *(bf16x8*)&Wsh[buf][1][(wc * 64 + 2 * 16 + rr) * 32 + pofs];
    w1 = *(bf16x8*)&Wsh[buf][1][(wc * 64 + 3 * 16 + rr) * 32 + pofs];
    if (more) {
      stW(tau + 1, 1);
      asm volatile("s_waitcnt vmcnt(4)" ::: "memory");
    }
    __builtin_amdgcn_sched_barrier(0);
    __builtin_amdgcn_s_barrier();
    asm volatile("s_waitcnt lgkmcnt(0)" ::: "memory");
    __builtin_amdgcn_sched_barrier(0);
    __builtin_amdgcn_s_setprio(1);
#pragma unroll
    for (int mi = 0; mi < 8; ++mi) {
      acc[mi][2] = MFMA_B16(af[mi], w0, acc[mi][2]);
      acc[mi][3] = MFMA_B16(af[mi], w1, acc[mi][3]);
    }
    __builtin_amdgcn_s_setprio(0);
    __builtin_amdgcn_s_barrier();
    __builtin_amdgcn_sched_barrier(0);
  }
  int cr = (lane >> 4) << 2;
  int cc = lane & 15;
  u16* outp = (n0 < DI) ? outU : outZ;
  int cb0 = (n0 < DI) ? n0 : (n0 - DI);
#pragma unroll
  for (int mi = 0; mi < 8; ++mi)
#pragma unroll
    for (int ni = 0; ni < 4; ++ni) {
      int row = m0 + wr * 128 + mi * 16 + cr;
      int col = cb0 + wc * 64 + ni * 16 + cc;
#pragma unroll
      for (int j = 0; j < 4; ++j)
        outp[(size_t)(row + j) * DI + col] = f2bf(acc[mi][ni][j]);
    }
}

// ---------------- GEMM (generic): 4-ring, stage-ahead-3, per-dir weight stride ----------------
#define EPI_F32  0
#define EPI_BF16 1
#define EPI_BIAS 2

template <int BN, int EPI, int SK = 1>
__global__ __launch_bounds__(256) void gemm_bt(const u16* __restrict__ A,
                                               const u16* __restrict__ W,
                                               void* __restrict__ outp,
                                               const float* __restrict__ bias,
                                               int N, int K, size_t wsd) {
  constexpr int BM = 128, BK = 32;
  constexpr int NF = BN / 32;
  constexpr int G = (BN == 128) ? 4 : 3;
  __shared__ u16 As[4][BM * BK];
  __shared__ u16 Wsh[4][BN * BK];
  int tid = threadIdx.x;
  int lane = tid & 63;
  int wv = tid >> 6;
  int wr = wv >> 1, wc = wv & 1;
  int m0 = blockIdx.x * BM;
  int n0 = (SK > 1) ? 0 : blockIdx.y * BN;
  int koff = (SK > 1) ? blockIdx.y * (K / SK) : 0;
  int KS = K / SK;
  int NK = KS / BK;
  const u16* Weff = W + (size_t)(m0 >> 13) * wsd;   // dir from row (0 if M<=8192)
  f32x4 acc[4][NF];
#pragma unroll
  for (int i = 0; i < 4; ++i)
#pragma unroll
    for (int j = 0; j < NF; ++j) acc[i][j] = (f32x4){0.f, 0.f, 0.f, 0.f};
  int rr = lane & 15;
  int kk = (lane >> 4) << 3;
  int l4 = lane >> 2;
  int c8 = (lane & 3) << 3;
  const u16* Ag = A + (size_t)(m0 + l4) * K + koff + c8;
  const u16* Wg = Weff + (size_t)(n0 + l4) * K + koff + c8;

  auto stage = [&](int k0, int buf) {
    gload16(Ag + (size_t)(wv * 16) * K + k0, &As[buf][wv * 512]);
    gload16(Ag + (size_t)((wv + 4) * 16) * K + k0, &As[buf][(wv + 4) * 512]);
    gload16(Wg + (size_t)(wv * 16) * K + k0, &Wsh[buf][wv * 512]);
    if (BN == 128)
      gload16(Wg + (size_t)((wv + 4) * 16) * K + k0, &Wsh[buf][(wv + 4) * 512]);
  };

  stage(0, 0); stage(BK, 1); stage(2 * BK, 2);
  for (int k = 0; k < NK; ++k) {
    if (k < NK - 2)
      asm volatile("s_waitcnt vmcnt(%0)" :: "n"(2 * G) : "memory");
    else if (k == NK - 2)
      asm volatile("s_waitcnt vmcnt(%0)" :: "n"(G) : "memory");
    else
      asm volatile("s_waitcnt vmcnt(0)" ::: "memory");
    __builtin_amdgcn_s_barrier();
    __builtin_amdgcn_sched_barrier(0);
    if (k + 3 < NK) stage((k + 3) * BK, (k + 3) & 3);
    __builtin_amdgcn_sched_barrier(0);
    int cur = k & 3;
    bf16x8 af[4], wf[NF];
#pragma unroll
    for (int mi = 0; mi < 4; ++mi)
      af[mi] = *(bf16x8*)&As[cur][(wr * 64 + mi * 16 + rr) * BK + kk];
#pragma unroll
    for (int ni = 0; ni < NF; ++ni)
      wf[ni] = *(bf16x8*)&Wsh[cur][(wc * (BN / 2) + ni * 16 + rr) * BK + kk];
#pragma unroll
    for (int mi = 0; mi < 4; ++mi)
#pragma unroll
      for (int ni = 0; ni < NF; ++ni)
        acc[mi][ni] = __builtin_amdgcn_mfma_f32_16x16x32_bf16(af[mi], wf[ni], acc[mi][ni], 0, 0, 0);
  }
  int cr = (lane >> 4) << 2;
  int cc = lane & 15;
  float* outF = (float*)outp +
      ((SK > 1) ? (size_t)blockIdx.y * (size_t)gridDim.x * BM * N : 0);
#pragma unroll
  for (int mi = 0; mi < 4; ++mi)
#pragma unroll
    for (int ni = 0; ni < NF; ++ni) {
      int row = m0 + wr * 64 + mi * 16 + cr;
      int col = n0 + wc * (BN / 2) + ni * 16 + cc;
      float bv = (EPI == EPI_BIAS) ? bias[col] : 0.f;
#pragma unroll
      for (int j = 0; j < 4; ++j) {
        float v = acc[mi][ni][j] + bv;
        if (EPI == EPI_BF16)
          ((u16*)outp)[(size_t)(row + j) * N + col] = f2bf(v);
        else
          outF[(size_t)(row + j) * N + col] = v;
      }
    }
}

// ---------------- depthwise causal conv + SiLU, both dirs ----------------
__global__ __launch_bounds__(256) void conv_k(const u16* __restrict__ xzu,
                                              const float* __restrict__ conv_w,
                                              const float* __restrict__ conv_b,
                                              int layer,
                                              u16* __restrict__ uh) {
  int idx = blockIdx.x * 256 + threadIdx.x;        // ROWS2*DI
  int c = idx & (DI - 1);
  int row = idx >> 10;
  int dir = row >> 13;
  int l = row & (L_ - 1);
  const float* cw = conv_w + (size_t)(dir * 2 + layer) * DI * 4;
  const float* cb = conv_b + (size_t)(dir * 2 + layer) * DI;
  float acc = cb[c];
#pragma unroll
  for (int j = 0; j < 4; ++j) {
    int ls = l + j - 3;
    if (ls >= 0)
      acc += bf2f(xzu[(size_t)(row + j - 3) * DI + c]) * cw[c * 4 + j];
  }
  float s = acc * sigmoidf_(acc);
  uh[idx] = f2bf(s);
}

// A-structure check
__device__ __forceinline__ bool a_fast(const float* alog, int d, float& a20) {
  a20 = -__expf(alog[d * NST]) * LN2R;
  bool fast = true;
#pragma unroll
  for (int n = 1; n < NST; ++n) {
    float an = -__expf(alog[d * NST + n]) * LN2R;
    fast &= (fabsf(an - (float)(n + 1) * a20) <= 1e-5f * (float)(n + 1) * fabsf(a20));
  }
  return fast;
}

// stage xs[CLEN][64] by summing 4 x_proj split-K partials (rowbase in rows)
__device__ __forceinline__ void stage_xs(float (*xs)[64], const float* xp,
                                         size_t rowbase, int tid) {
  size_t base = rowbase * 64;
  const float4v* s0 = (const float4v*)(xp + base);
  const float4v* s1 = (const float4v*)(xp + (size_t)ROWS2 * 64 + base);
  const float4v* s2 = (const float4v*)(xp + (size_t)2 * ROWS2 * 64 + base);
  const float4v* s3 = (const float4v*)(xp + (size_t)3 * ROWS2 * 64 + base);
  float4v* dst = (float4v*)&xs[0][0];
#pragma unroll
  for (int i = 0; i < CLEN / 16; ++i)
    dst[tid + i * 256] = s0[tid + i * 256] + s1[tid + i * 256] +
                         s2[tid + i * 256] + s3[tid + i * 256];
}

// dt = softplus(dot(xs[t][0..31], w2) + bias) — shared by pass1/pass3 (bit-identical)
__device__ __forceinline__ float dt_of(const float (*xs)[64], int t,
                                       const f32x2* w2, float bias) {
  f32x2 a2 = {bias, 0.f};
  const f32x2* xr2 = (const f32x2*)&xs[t][0];
#pragma unroll
  for (int j = 0; j < 16; ++j) a2 = pk_fma(xr2[j], w2[j], a2);
  float a = a2.x + a2.y;
  return (a > 15.f) ? a : __logf(1.f + __expf(a));
}

// ---------------- fused dt + scan pass 1 (both dirs) ----------------
__global__ __launch_bounds__(256) void dtscan1_k(const u16* __restrict__ uh,
                                                 const float* __restrict__ xp,
                                                 const float* __restrict__ dtw_t,
                                                 const float* __restrict__ dtb,
                                                 const float* __restrict__ alog_,
                                                 int layer,
                                                 float* __restrict__ chk) {
  __shared__ float xs[CLEN][64];                  // 16 kB
  int blk = blockIdx.x;            // 1024 = nb(8) x chunks(32) x dgroup(4)
  int db = blk & 3;
  int c  = (blk >> 2) & (NCHUNK - 1);
  int nb = blk >> 7;               // dir*4 + b
  int dir = nb >> 2;
  int tid = threadIdx.x;
  int d  = db * 256 + tid;
  int li = dir * 2 + layer;
  const float* dtwT = dtw_t + (size_t)li * DTR * DI;
  const float* alog = alog_ + (size_t)li * DI * NST;
  int t0 = c * CLEN;
  size_t rowbase = (size_t)nb * L_ + t0;          // nb*2048 + t0 == global row
  stage_xs(xs, xp, rowbase, tid);
  f32x2 w2[16];
#pragma unroll
  for (int j = 0; j < 16; ++j)
    w2[j] = (f32x2){dtwT[(size_t)(2 * j) * DI + d], dtwT[(size_t)(2 * j + 1) * DI + d]};
  float bias = dtb[(size_t)li * DI + d];
  float a20;
  bool fast = a_fast(alog, d, a20);
  __syncthreads();
  float S = 0.f;
  size_t ubase = rowbase * DI + d;
  f32x2 h2[8];
#pragma unroll
  for (int q = 0; q < 8; ++q) h2[q] = (f32x2){0.f, 0.f};
  for (int t = 0; t < CLEN; ++t) {
    float dtv = dt_of(xs, t, w2, bias);
    float du = dtv * bf2f(uh[ubase]);
    S += dtv;
    if (fast) {
      float p1 = exp2f(dtv * a20);
      float p2 = p1 * p1;
      f32x2 pw = {p1, p2};
      f32x2 pst = {p2, p2};
      f32x2 du2 = {du, du};
#pragma unroll
      for (int k = 0; k < 4; ++k) {
        f32x4 bv = *(const f32x4*)&xs[t][DTR + k * 4];
        f32x2 blo = __builtin_shufflevector(bv, bv, 0, 1);
        f32x2 bhi = __builtin_shufflevector(bv, bv, 2, 3);
        h2[2 * k]     = pk_fma(pw, h2[2 * k], pk_mul(du2, blo));
        pw = pk_mul(pw, pst);
        h2[2 * k + 1] = pk_fma(pw, h2[2 * k + 1], pk_mul(du2, bhi));
        if (k < 3) pw = pk_mul(pw, pst);
      }
    } else {
#pragma unroll
      for (int q = 0; q < 8; ++q) {
        float e0 = exp2f(dtv * -__expf(alog[d * NST + 2 * q]) * LN2R);
        float e1 = exp2f(dtv * -__expf(alog[d * NST + 2 * q + 1]) * LN2R);
        f32x2 bv = *(const f32x2*)&xs[t][DTR + q * 2];
        h2[q] = pk_fma((f32x2){e0, e1}, h2[q], pk_mul((f32x2){du, du}, bv));
      }
    }
    ubase += DI;
  }
  const size_t H = (size_t)8 * NCHUNK * DI * NST;
  size_t idx = ((size_t)(nb * NCHUNK + c) * DI + d) * NST;
#pragma unroll
  for (int n = 0; n < NST; ++n) {
    float an = -__expf(alog[d * NST + n]) * LN2R;
    chk[idx + n]     = exp2f(an * S);
    chk[H + idx + n] = (n & 1) ? h2[n >> 1].y : h2[n >> 1].x;
  }
}

// pass 2: sequential chunk combine (both dirs)
__global__ __launch_bounds__(256) void scan2_k(float* __restrict__ chk) {
  int j = blockIdx.x * 256 + threadIdx.x;   // 131072 = 8*DI*NST
  int n = j & 15;
  int d = (j >> 4) & (DI - 1);
  int nb = j >> 14;
  const size_t H = (size_t)8 * NCHUNK * DI * NST;
  float h = 0.f;
  for (int c = 0; c < NCHUNK; ++c) {
    size_t idx = ((size_t)(nb * NCHUNK + c) * DI + d) * NST + n;
    float a = chk[idx];
    float hl = chk[H + idx];
    chk[H + idx] = h;
    h = a * h + hl;
  }
}

// pass 3: recompute dt from LDS xs; re-run chunk; fused gate -> bf16 yg
__global__ __launch_bounds__(256) void scan3_k(const u16* __restrict__ uh,
                                               const float* __restrict__ xp,
                                               const float* __restrict__ dtw_t,
                                               const float* __restrict__ dtb,
                                               const float* __restrict__ alog_,
                                               const float* __restrict__ Dp,
                                               int layer,
                                               const float* __restrict__ chk,
                                               const u16* __restrict__ xzz,
                                               u16* __restrict__ yg) {
  __shared__ float xs[CLEN][64];
  int blk = blockIdx.x;
  int db = blk & 3;
  int c  = (blk >> 2) & (NCHUNK - 1);
  int nb = blk >> 7;
  int dir = nb >> 2;
  int tid = threadIdx.x;
  int d  = db * 256 + tid;
  int li = dir * 2 + layer;
  const float* dtwT = dtw_t + (size_t)li * DTR * DI;
  const float* alog = alog_ + (size_t)li * DI * NST;
  int t0 = c * CLEN;
  size_t rowbase = (size_t)nb * L_ + t0;
  stage_xs(xs, xp, rowbase, tid);
  f32x2 w2[16];
#pragma unroll
  for (int j = 0; j < 16; ++j)
    w2[j] = (f32x2){dtwT[(size_t)(2 * j) * DI + d], dtwT[(size_t)(2 * j + 1) * DI + d]};
  float bias = dtb[(size_t)li * DI + d];
  float a20;
  bool fast = a_fast(alog, d, a20);
  const size_t H = (size_t)8 * NCHUNK * DI * NST;
  size_t cidx = ((size_t)(nb * NCHUNK + c) * DI + d) * NST;
  f32x2 h2[8];
#pragma unroll
  for (int q = 0; q < 8; ++q) h2[q] = *(const f32x2*)&chk[H + cidx + 2 * q];
  float Dv = Dp[(size_t)li * DI + d];
  __syncthreads();
  size_t ubase = rowbase * DI + d;
  if (fast) {
    for (int t = 0; t < CLEN; ++t) {
      float dtv = dt_of(xs, t, w2, bias);
      float uv  = bf2f(uh[ubase]);
      float du  = dtv * uv;
      float p1 = exp2f(dtv * a20);
      float p2 = p1 * p1;
      f32x2 pw = {p1, p2};
      f32x2 pst = {p2, p2};
      f32x2 du2 = {du, du};
      f32x2 acc2 = {0.f, 0.f};
#pragma unroll
      for (int k = 0; k < 4; ++k) {
        f32x4 bv = *(const f32x4*)&xs[t][DTR + k * 4];
        f32x4 cv = *(const f32x4*)&xs[t][DTR + NST + k * 4];
        f32x2 blo = __builtin_shufflevector(bv, bv, 0, 1);
        f32x2 bhi = __builtin_shufflevector(bv, bv, 2, 3);
        f32x2 clo = __builtin_shufflevector(cv, cv, 0, 1);
        f32x2 chi = __builtin_shufflevector(cv, cv, 2, 3);
        h2[2 * k]     = pk_fma(pw, h2[2 * k], pk_mul(du2, blo));
        acc2          = pk_fma(h2[2 * k], clo, acc2);
        pw = pk_mul(pw, pst);
        h2[2 * k + 1] = pk_fma(pw, h2[2 * k + 1], pk_mul(du2, bhi));
        acc2          = pk_fma(h2[2 * k + 1], chi, acc2);
        if (k < 3) pw = pk_mul(pw, pst);
      }
      float y = acc2.x + acc2.y + uv * Dv;
      float z = bf2f(xzz[ubase]);
      yg[ubase] = f2bf(y * z * sigmoidf_(z));
      ubase += DI;
    }
  } else {
    float A2[NST];
#pragma unroll
    for (int n = 0; n < NST; ++n) A2[n] = -__expf(alog[d * NST + n]) * LN2R;
    for (int t = 0; t < CLEN; ++t) {
      float dtv = dt_of(xs, t, w2, bias);
      float uv  = bf2f(uh[ubase]);
      float du  = dtv * uv;
      f32x2 acc2 = {0.f, 0.f};
#pragma unroll
      for (int q = 0; q < 8; ++q) {
        f32x2 bv = *(const f32x2*)&xs[t][DTR + q * 2];
        f32x2 cv = *(const f32x2*)&xs[t][DTR + NST + q * 2];
        f32x2 e = {exp2f(dtv * A2[2 * q]), exp2f(dtv * A2[2 * q + 1])};
        h2[q] = pk_fma(e, h2[q], pk_mul((f32x2){du, du}, bv));
        acc2 = pk_fma(h2[q], cv, acc2);
      }
      float y = acc2.x + acc2.y + uv * Dv;
      float z = bf2f(xzz[ubase]);
      yg[ubase] = f2bf(y * z * sigmoidf_(z));
      ubase += DI;
    }
  }
}

// ---------------- final rmsnorm(hid+res) -> concat buffer, both dirs ----------------
__global__ __launch_bounds__(256) void fincat_k(const float* __restrict__ hid,
                                                const float* __restrict__ res,
                                                const float* __restrict__ norm_f,
                                                u16* __restrict__ cat) {
  int row = blockIdx.x;                 // 0..16383
  int dir = row >> 13;
  const float* w = norm_f + (size_t)dir * DM;
  int tid = threadIdx.x;
  int base = row * DM;
  float x0 = hid[base + tid] + res[base + tid];
  float x1 = hid[base + 256 + tid] + res[base + 256 + tid];
  float s = x0 * x0 + x1 * x1;
  for (int off = 32; off; off >>= 1) s += __shfl_xor(s, off);
  __shared__ float ps[4];
  if (!(tid & 63)) ps[tid >> 6] = s;
  __syncthreads();
  float tot = ps[0] + ps[1] + ps[2] + ps[3];
  float rs = 1.f / sqrtf(tot / (float)DM + 1e-5f);
  int r = row & (ROWS - 1);
  int b = r >> 11, l = r & (L_ - 1);
  size_t drow = dir ? ((size_t)(b << 11) + (L_ - 1 - l)) : (size_t)r;
  size_t obase = drow * (2 * DM) + (size_t)dir * DM;
  cat[obase + tid]       = f2bf(x0 * rs * w[tid]);
  cat[obase + 256 + tid] = f2bf(x1 * rs * w[tid + 256]);
}

extern "C" void kernel_launch(void* const* d_in, const int* in_sizes, int n_in,
                              void* d_out, int out_size, void* d_ws, size_t ws_size,
                              hipStream_t stream) {
  const int*   ids      = (const int*)d_in[0];
  const float* embed    = (const float*)d_in[2];
  const float* in_w     = (const float*)d_in[3];
  const float* conv_w   = (const float*)d_in[4];
  const float* conv_b   = (const float*)d_in[5];
  const float* x_w      = (const float*)d_in[6];
  const float* dt_w     = (const float*)d_in[7];
  const float* dt_bias  = (const float*)d_in[8];
  const float* A_log    = (const float*)d_in[9];
  const float* Dp       = (const float*)d_in[10];
  const float* out_w    = (const float*)d_in[11];
  const float* norm_w   = (const float*)d_in[12];
  const float* norm_f   = (const float*)d_in[13];
  const float* proj_w   = (const float*)d_in[14];
  const float* proj_b   = (const float*)d_in[15];

  char* ws = (char*)d_ws;
  size_t off = 0;
  auto alloc = [&](size_t bytes) {
    void* p = ws + off;
    off += (bytes + 255) & ~(size_t)255;
    return p;
  };
  float* res  = (float*)alloc((size_t)ROWS2 * DM * 4);       // 33.6 MB
  float* hid  = (float*)alloc((size_t)ROWS2 * DM * 4);       // 33.6 MB (x_proj partials alias)
  u16*   xnyg = (u16*)alloc((size_t)ROWS2 * DI * 2);         // 33.6 MB (xn | yg)
  u16*   xzz  = (u16*)alloc((size_t)ROWS2 * DI * 2);         // 33.6 MB (z half)
  void*  shrd = alloc((size_t)ROWS2 * DI * 2);               // 33.6 MB (xzu | chk | cat)
  u16*   u_h  = (u16*)alloc((size_t)ROWS2 * DI * 2);         // 33.6 MB
  const int N_IN  = 4 * 2 * DI * DM;
  const int N_XW  = 4 * 64 * DI;
  const int N_OW  = 4 * DM * DI;
  const int N_PW  = DM * 2 * DM;
  const int N_DTW = 4 * DTR * DI;
  u16*   in_wb  = (u16*)alloc((size_t)N_IN * 2);             //  8.4 MB
  u16*   x_wb   = (u16*)alloc((size_t)N_XW * 2);
  u16*   out_wb = (u16*)alloc((size_t)N_OW * 2);
  u16*   pr_wb  = (u16*)alloc((size_t)N_PW * 2);
  float* dtw_t  = (float*)alloc((size_t)N_DTW * 4);
  if (off > ws_size) return;   // clean fail if ws too small (diagnosable)

  u16*   xzu = (u16*)shrd;
  float* chk = (float*)shrd;
  u16*   cat = (u16*)shrd;

  cvt_k<<<(N_IN / 4 + 255) / 256, 256, 0, stream>>>(in_w, in_wb, N_IN / 4);
  cvt_k<<<(N_XW / 4 + 255) / 256, 256, 0, stream>>>(x_w, x_wb, N_XW / 4);
  cvt_k<<<(N_OW / 4 + 255) / 256, 256, 0, stream>>>(out_w, out_wb, N_OW / 4);
  cvt_k<<<(N_PW / 4 + 255) / 256, 256, 0, stream>>>(proj_w, pr_wb, N_PW / 4);
  trp_k<<<N_DTW / 256, 256, 0, stream>>>(dt_w, dtw_t);

  embed_k<<<ROWS2 * DM / 256, 256, 0, stream>>>(ids, embed, res);
  for (int i = 0; i < 2; ++i) {
    if (i == 0)
      addnorm_k<false><<<ROWS2, 256, 0, stream>>>(res, hid, norm_w, i, xnyg);
    else
      addnorm_k<true><<<ROWS2, 256, 0, stream>>>(res, hid, norm_w, i, xnyg);
    gemm8p_k<<<512, 512, 0, stream>>>(
        xnyg, in_wb + (size_t)i * 2 * DI * DM, xzu, xzz, DM);
    conv_k<<<ROWS2 * DI / 256, 256, 0, stream>>>(xzu, conv_w, conv_b, i, u_h);
    gemm_bt<64, EPI_F32, 4><<<dim3(ROWS2 / 128, 4), 256, 0, stream>>>(
        u_h, x_wb + (size_t)i * 64 * DI, hid, nullptr, 64, DI, (size_t)2 * 64 * DI);
    dtscan1_k<<<1024, 256, 0, stream>>>(u_h, hid, dtw_t, dt_bias, A_log, i, chk);
    scan2_k<<<512, 256, 0, stream>>>(chk);
    scan3_k<<<1024, 256, 0, stream>>>(u_h, hid, dtw_t, dt_bias, A_log, Dp, i,
                                      chk, xzz, xnyg);
    gemm_bt<64, EPI_F32><<<dim3(ROWS2 / 128, DM / 64), 256, 0, stream>>>(
        xnyg, out_wb + (size_t)i * DM * DI, hid, nullptr, DM, DI, (size_t)2 * DM * DI);
  }
  fincat_k<<<ROWS2, 256, 0, stream>>>(hid, res, norm_f, cat);
  gemm_bt<64, EPI_BIAS><<<dim3(ROWS / 128, DM / 64), 256, 0, stream>>>(
      cat, pr_wb, (float*)d_out, proj_b, DM, DI, 0);
}

// Round 15
// 771.066 us; speedup vs baseline: 1.0930x; 1.0055x over previous
//
#include <hip/hip_runtime.h>
#include <hip/hip_bf16.h>

#define B_   4
#define L_   2048
#define DM   512
#define DI   1024
#define NST  16
#define DTR  32
#define ROWS  (B_ * L_)        // 8192
#define ROWS2 (2 * ROWS)       // 16384 (both directions)
#define NCHUNK 32
#define CLEN  (L_ / NCHUNK)    // 64
#define LN2R 1.4426950408889634f

typedef unsigned short u16;
typedef __attribute__((ext_vector_type(8))) short bf16x8;
typedef __attribute__((ext_vector_type(4))) float f32x4;
typedef __attribute__((ext_vector_type(4))) float float4v;
typedef __attribute__((ext_vector_type(2))) float f32x2;

__device__ __forceinline__ float bf2f(u16 h) {
  union { unsigned int u; float f; } v; v.u = ((unsigned int)h) << 16; return v.f;
}
__device__ __forceinline__ u16 f2bf(float f) {
  union { float f; unsigned int u; } v; v.f = f;
  unsigned int u = v.u;
  if ((u & 0x7fffffffu) > 0x7f800000u) return (u16)((u >> 16) | 0x0040u);
  return (u16)((u + 0x7fffu + ((u >> 16) & 1u)) >> 16);
}
__device__ __forceinline__ float sigmoidf_(float x) { return 1.f / (1.f + __expf(-x)); }

__device__ __forceinline__ f32x2 pk_mul(f32x2 a, f32x2 b) {
  f32x2 d; asm("v_pk_mul_f32 %0, %1, %2" : "=v"(d) : "v"(a), "v"(b)); return d;
}
__device__ __forceinline__ f32x2 pk_fma(f32x2 a, f32x2 b, f32x2 c) {
  f32x2 d; asm("v_pk_fma_f32 %0, %1, %2, %3" : "=v"(d) : "v"(a), "v"(b), "v"(c)); return d;
}

__device__ __forceinline__ void gload16(const u16* g, u16* l) {
  __builtin_amdgcn_global_load_lds(
      (const __attribute__((address_space(1))) void*)g,
      (__attribute__((address_space(3))) void*)l, 16, 0, 0);
}

// ---------------- f32 -> bf16 weight conversion ----------------
__global__ __launch_bounds__(256) void cvt_k(const float* __restrict__ in,
                                             u16* __restrict__ out, int n4) {
  int i = blockIdx.x * 256 + threadIdx.x;
  if (i >= n4) return;
  float4v v = *(const float4v*)&in[i * 4];
  u16 o[4];
  o[0] = f2bf(v.x); o[1] = f2bf(v.y); o[2] = f2bf(v.z); o[3] = f2bf(v.w);
  *(ulong1*)&out[i * 4] = *(ulong1*)o;
}

// ---------------- dt_w transpose: [4][DI][DTR] -> [4][DTR][DI] (f32) ----------------
__global__ __launch_bounds__(256) void trp_k(const float* __restrict__ in,
                                             float* __restrict__ out) {
  int o = blockIdx.x * 256 + threadIdx.x;
  int li = o >> 15;
  int k = (o >> 10) & (DTR - 1);
  int d = o & (DI - 1);
  out[o] = in[((size_t)li * DI + d) * DTR + k];
}

// ---------------- embed gather, both directions ----------------
__global__ __launch_bounds__(256) void embed_k(const int* __restrict__ ids,
                                               const float* __restrict__ emb,
                                               float* __restrict__ res) {
  int idx = blockIdx.x * 256 + threadIdx.x;   // ROWS2*DM
  int c = idx & (DM - 1);
  int row = idx >> 9;                          // 0..16383
  int dir = row >> 13;
  int r = row & (ROWS - 1);
  int b = r >> 11;
  int l = r & (L_ - 1);
  int sl = dir ? (L_ - 1 - l) : l;
  int id = ids[(b << 11) + sl];
  res[idx] = emb[(size_t)dir * 128 * DM + id * DM + c];
}

// ---------------- (res += hid); xn = rmsnorm(res) * w (per-dir weights) ----------------
template <bool ADD>
__global__ __launch_bounds__(256) void addnorm_k(float* __restrict__ res,
                                                 const float* __restrict__ hid,
                                                 const float* __restrict__ norm_w,
                                                 int layer,
                                                 u16* __restrict__ xn) {
  int row = blockIdx.x;                        // 0..16383
  int dir = row >> 13;
  const float* w = norm_w + (size_t)(dir * 2 + layer) * DM;
  int tid = threadIdx.x;
  int base = row * DM;
  float x0 = res[base + tid];
  float x1 = res[base + 256 + tid];
  if (ADD) {
    x0 += hid[base + tid];
    x1 += hid[base + 256 + tid];
    res[base + tid] = x0;
    res[base + 256 + tid] = x1;
  }
  float s = x0 * x0 + x1 * x1;
  for (int off = 32; off; off >>= 1) s += __shfl_xor(s, off);
  __shared__ float ps[4];
  if (!(tid & 63)) ps[tid >> 6] = s;
  __syncthreads();
  float tot = ps[0] + ps[1] + ps[2] + ps[3];
  float rs = 1.f / sqrtf(tot / (float)DM + 1e-5f);
  xn[base + tid]       = f2bf(x0 * rs * w[tid]);
  xn[base + 256 + tid] = f2bf(x1 * rs * w[tid + 256]);
}

// ---------------- in_proj: 256x256 tile, 8-phase schedule, M=16384 both dirs ----------------
#define MFMA_B16(a, b, c) __builtin_amdgcn_mfma_f32_16x16x32_bf16(a, b, c, 0, 0, 0)

__global__ __launch_bounds__(512) void gemm8p_k(const u16* __restrict__ A,
                                                const u16* __restrict__ W,   // layer-i base (dir0)
                                                u16* __restrict__ outU,      // [row][DI] u-half
                                                u16* __restrict__ outZ,      // [row][DI] z-half
                                                int K) {
  __shared__ u16 As[2][2][256 * 32];    // 64 kB
  __shared__ u16 Wsh[2][2][256 * 32];   // 64 kB
  int tid = threadIdx.x;
  int lane = tid & 63;
  int wv = tid >> 6;
  int wr = wv >> 2, wc = wv & 3;        // 2M x 4N waves
  int bid = blockIdx.x;                 // 512 blocks: 64 mt x 8 nt
  int xcd = bid & 7, jj = bid >> 3;
  int mt = xcd * 8 + (jj & 7);          // 0..63
  int nt = jj >> 3;                     // 0..7
  int m0 = mt * 256, n0 = nt * 256;
  const u16* Weff = W + (size_t)(m0 >> 13) * (size_t)2 * (2 * DI) * DM;
  f32x4 acc[8][4];
#pragma unroll
  for (int i = 0; i < 8; ++i)
#pragma unroll
    for (int j = 0; j < 4; ++j) acc[i][j] = (f32x4){0.f, 0.f, 0.f, 0.f};
  int rr = lane & 15;
  int sl = lane >> 4;
  int pofs = ((sl + (rr >> 1)) & 3) * 8;
  int lr = lane >> 2;
  int ls = ((lane & 3) - (lr >> 1)) & 3;

  auto stA = [&](int tau, int ks) {
    int buf = tau & 1;
#pragma unroll
    for (int j = 0; j < 2; ++j)
      gload16(A + (size_t)(m0 + j * 128 + wv * 16 + lr) * K + tau * 64 + ks * 32 + ls * 8,
              &As[buf][ks][(j * 128 + wv * 16) * 32]);
  };
  auto stW = [&](int tau, int ks) {
    int buf = tau & 1;
#pragma unroll
    for (int j = 0; j < 2; ++j)
      gload16(Weff + (size_t)(n0 + j * 128 + wv * 16 + lr) * K + tau * 64 + ks * 32 + ls * 8,
              &Wsh[buf][ks][(j * 128 + wv * 16) * 32]);
  };

  int NT = K / 64;
  stA(0, 0); stW(0, 0); stA(0, 1); stW(0, 1);
  asm volatile("s_waitcnt vmcnt(4)" ::: "memory");
  __builtin_amdgcn_sched_barrier(0);
  __builtin_amdgcn_s_barrier();
  __builtin_amdgcn_sched_barrier(0);

  for (int tau = 0; tau < NT; ++tau) {
    int buf = tau & 1;
    bool more = (tau + 1 < NT);
    bf16x8 af[8], w0, w1;
    // phase 1: ks=0, ni 0-1
#pragma unroll
    for (int mi = 0; mi < 8; ++mi)
      af[mi] = *(bf16x8*)&As[buf][0][(wr * 128 + mi * 16 + rr) * 32 + pofs];
    w0 = *(bf16x8*)&Wsh[buf][0][(wc * 64 + 0 * 16 + rr) * 32 + pofs];
    w1 = *(bf16x8*)&Wsh[buf][0][(wc * 64 + 1 * 16 + rr) * 32 + pofs];
    if (more) stA(tau + 1, 0);
    __builtin_amdgcn_sched_barrier(0);
    __builtin_amdgcn_s_barrier();
    asm volatile("s_waitcnt lgkmcnt(0)" ::: "memory");
    __builtin_amdgcn_sched_barrier(0);
    __builtin_amdgcn_s_setprio(1);
#pragma unroll
    for (int mi = 0; mi < 8; ++mi) {
      acc[mi][0] = MFMA_B16(af[mi], w0, acc[mi][0]);
      acc[mi][1] = MFMA_B16(af[mi], w1, acc[mi][1]);
    }
    __builtin_amdgcn_s_setprio(0);
    __builtin_amdgcn_s_barrier();
    __builtin_amdgcn_sched_barrier(0);
    // phase 2: ks=0, ni 2-3
    w0 = *(bf16x8*)&Wsh[buf][0][(wc * 64 + 2 * 16 + rr) * 32 + pofs];
    w1 = *(bf16x8*)&Wsh[buf][0][(wc * 64 + 3 * 16 + rr) * 32 + pofs];
    if (more) {
      stW(tau + 1, 0);
      asm volatile("s_waitcnt vmcnt(4)" ::: "memory");
    } else {
      asm volatile("s_waitcnt vmcnt(0)" ::: "memory");
    }
    __builtin_amdgcn_sched_barrier(0);
    __builtin_amdgcn_s_barrier();
    asm volatile("s_waitcnt lgkmcnt(0)" ::: "memory");
    __builtin_amdgcn_sched_barrier(0);
    __builtin_amdgcn_s_setprio(1);
#pragma unroll
    for (int mi = 0; mi < 8; ++mi) {
      acc[mi][2] = MFMA_B16(af[mi], w0, acc[mi][2]);
      acc[mi][3] = MFMA_B16(af[mi], w1, acc[mi][3]);
    }
    __builtin_amdgcn_s_setprio(0);
    __builtin_amdgcn_s_barrier();
    __builtin_amdgcn_sched_barrier(0);
    // phase 3: ks=1, ni 0-1
#pragma unroll
    for (int mi = 0; mi < 8; ++mi)
      af[mi] = *(bf16x8*)&As[buf][1][(wr * 128 + mi * 16 + rr) * 32 + pofs];
    w0 = *(bf16x8*)&Wsh[buf][1][(wc * 64 + 0 * 16 + rr) * 32 + pofs];
    w1 = *(bf16x8*)&Wsh[buf][1][(wc * 64 + 1 * 16 + rr) * 32 + pofs];
    if (more) stA(tau + 1, 1);
    __builtin_amdgcn_sched_barrier(0);
    __builtin_amdgcn_s_barrier();
    asm volatile("s_waitcnt lgkmcnt(0)" ::: "memory");
    __builtin_amdgcn_sched_barrier(0);
    __builtin_amdgcn_s_setprio(1);
#pragma unroll
    for (int mi = 0; mi < 8; ++mi) {
      acc[mi][0] = MFMA_B16(af[mi], w0, acc[mi][0]);
      acc[mi][1] = MFMA_B16(af[mi], w1, acc[mi][1]);
    }
    __builtin_amdgcn_s_setprio(0);
    __builtin_amdgcn_s_barrier();
    __builtin_amdgcn_sched_barrier(0);
    // phase 4: ks=1, ni 2-3
    w0 = *(bf16x8*)&Wsh[buf][1][(wc * 64 + 2 * 16 + rr) * 32 + pofs];
    w1 = *(bf16x8*)&Wsh[buf][1][(wc * 64 + 3 * 16 + rr) * 32 + pofs];
    if (more) {
      stW(tau + 1, 1);
      asm volatile("s_waitcnt vmcnt(4)" ::: "memory");
    }
    __builtin_amdgcn_sched_barrier(0);
    __builtin_amdgcn_s_barrier();
    asm volatile("s_waitcnt lgkmcnt(0)" ::: "memory");
    __builtin_amdgcn_sched_barrier(0);
    __builtin_amdgcn_s_setprio(1);
#pragma unroll
    for (int mi = 0; mi < 8; ++mi) {
      acc[mi][2] = MFMA_B16(af[mi], w0, acc[mi][2]);
      acc[mi][3] = MFMA_B16(af[mi], w1, acc[mi][3]);
    }
    __builtin_amdgcn_s_setprio(0);
    __builtin_amdgcn_s_barrier();
    __builtin_amdgcn_sched_barrier(0);
  }
  int cr = (lane >> 4) << 2;
  int cc = lane & 15;
  u16* outp = (n0 < DI) ? outU : outZ;
  int cb0 = (n0 < DI) ? n0 : (n0 - DI);
#pragma unroll
  for (int mi = 0; mi < 8; ++mi)
#pragma unroll
    for (int ni = 0; ni < 4; ++ni) {
      int row = m0 + wr * 128 + mi * 16 + cr;
      int col = cb0 + wc * 64 + ni * 16 + cc;
#pragma unroll
      for (int j = 0; j < 4; ++j)
        outp[(size_t)(row + j) * DI + col] = f2bf(acc[mi][ni][j]);
    }
}

// ---------------- GEMM (generic): 4-ring, stage-ahead-3, per-dir weight stride ----------------
#define EPI_F32  0
#define EPI_BF16 1
#define EPI_BIAS 2

template <int BN, int EPI, int SK = 1>
__global__ __launch_bounds__(256) void gemm_bt(const u16* __restrict__ A,
                                               const u16* __restrict__ W,
                                               void* __restrict__ outp,
                                               const float* __restrict__ bias,
                                               int N, int K, size_t wsd) {
  constexpr int BM = 128, BK = 32;
  constexpr int NF = BN / 32;
  constexpr int G = (BN == 128) ? 4 : 3;
  __shared__ u16 As[4][BM * BK];
  __shared__ u16 Wsh[4][BN * BK];
  int tid = threadIdx.x;
  int lane = tid & 63;
  int wv = tid >> 6;
  int wr = wv >> 1, wc = wv & 1;
  int m0 = blockIdx.x * BM;
  int n0 = (SK > 1) ? 0 : blockIdx.y * BN;
  int koff = (SK > 1) ? blockIdx.y * (K / SK) : 0;
  int KS = K / SK;
  int NK = KS / BK;
  const u16* Weff = W + (size_t)(m0 >> 13) * wsd;
  f32x4 acc[4][NF];
#pragma unroll
  for (int i = 0; i < 4; ++i)
#pragma unroll
    for (int j = 0; j < NF; ++j) acc[i][j] = (f32x4){0.f, 0.f, 0.f, 0.f};
  int rr = lane & 15;
  int kk = (lane >> 4) << 3;
  int l4 = lane >> 2;
  int c8 = (lane & 3) << 3;
  const u16* Ag = A + (size_t)(m0 + l4) * K + koff + c8;
  const u16* Wg = Weff + (size_t)(n0 + l4) * K + koff + c8;

  auto stage = [&](int k0, int buf) {
    gload16(Ag + (size_t)(wv * 16) * K + k0, &As[buf][wv * 512]);
    gload16(Ag + (size_t)((wv + 4) * 16) * K + k0, &As[buf][(wv + 4) * 512]);
    gload16(Wg + (size_t)(wv * 16) * K + k0, &Wsh[buf][wv * 512]);
    if (BN == 128)
      gload16(Wg + (size_t)((wv + 4) * 16) * K + k0, &Wsh[buf][(wv + 4) * 512]);
  };

  stage(0, 0); stage(BK, 1); stage(2 * BK, 2);
  for (int k = 0; k < NK; ++k) {
    if (k < NK - 2)
      asm volatile("s_waitcnt vmcnt(%0)" :: "n"(2 * G) : "memory");
    else if (k == NK - 2)
      asm volatile("s_waitcnt vmcnt(%0)" :: "n"(G) : "memory");
    else
      asm volatile("s_waitcnt vmcnt(0)" ::: "memory");
    __builtin_amdgcn_s_barrier();
    __builtin_amdgcn_sched_barrier(0);
    if (k + 3 < NK) stage((k + 3) * BK, (k + 3) & 3);
    __builtin_amdgcn_sched_barrier(0);
    int cur = k & 3;
    bf16x8 af[4], wf[NF];
#pragma unroll
    for (int mi = 0; mi < 4; ++mi)
      af[mi] = *(bf16x8*)&As[cur][(wr * 64 + mi * 16 + rr) * BK + kk];
#pragma unroll
    for (int ni = 0; ni < NF; ++ni)
      wf[ni] = *(bf16x8*)&Wsh[cur][(wc * (BN / 2) + ni * 16 + rr) * BK + kk];
#pragma unroll
    for (int mi = 0; mi < 4; ++mi)
#pragma unroll
      for (int ni = 0; ni < NF; ++ni)
        acc[mi][ni] = __builtin_amdgcn_mfma_f32_16x16x32_bf16(af[mi], wf[ni], acc[mi][ni], 0, 0, 0);
  }
  int cr = (lane >> 4) << 2;
  int cc = lane & 15;
  float* outF = (float*)outp +
      ((SK > 1) ? (size_t)blockIdx.y * (size_t)gridDim.x * BM * N : 0);
#pragma unroll
  for (int mi = 0; mi < 4; ++mi)
#pragma unroll
    for (int ni = 0; ni < NF; ++ni) {
      int row = m0 + wr * 64 + mi * 16 + cr;
      int col = n0 + wc * (BN / 2) + ni * 16 + cc;
      float bv = (EPI == EPI_BIAS) ? bias[col] : 0.f;
#pragma unroll
      for (int j = 0; j < 4; ++j) {
        float v = acc[mi][ni][j] + bv;
        if (EPI == EPI_BF16)
          ((u16*)outp)[(size_t)(row + j) * N + col] = f2bf(v);
        else
          outF[(size_t)(row + j) * N + col] = v;
      }
    }
}

// ---------------- depthwise causal conv + SiLU, both dirs ----------------
__global__ __launch_bounds__(256) void conv_k(const u16* __restrict__ xzu,
                                              const float* __restrict__ conv_w,
                                              const float* __restrict__ conv_b,
                                              int layer,
                                              u16* __restrict__ uh) {
  int idx = blockIdx.x * 256 + threadIdx.x;        // ROWS2*DI
  int c = idx & (DI - 1);
  int row = idx >> 10;
  int dir = row >> 13;
  int l = row & (L_ - 1);
  const float* cw = conv_w + (size_t)(dir * 2 + layer) * DI * 4;
  const float* cb = conv_b + (size_t)(dir * 2 + layer) * DI;
  float acc = cb[c];
#pragma unroll
  for (int j = 0; j < 4; ++j) {
    int ls = l + j - 3;
    if (ls >= 0)
      acc += bf2f(xzu[(size_t)(row + j - 3) * DI + c]) * cw[c * 4 + j];
  }
  float s = acc * sigmoidf_(acc);
  uh[idx] = f2bf(s);
}

// A-structure check
__device__ __forceinline__ bool a_fast(const float* alog, int d, float& a20) {
  a20 = -__expf(alog[d * NST]) * LN2R;
  bool fast = true;
#pragma unroll
  for (int n = 1; n < NST; ++n) {
    float an = -__expf(alog[d * NST + n]) * LN2R;
    fast &= (fabsf(an - (float)(n + 1) * a20) <= 1e-5f * (float)(n + 1) * fabsf(a20));
  }
  return fast;
}

// stage xs[CLEN][64] by summing 4 x_proj split-K partials (rowbase in rows)
__device__ __forceinline__ void stage_xs(float (*xs)[64], const float* xp,
                                         size_t rowbase, int tid) {
  size_t base = rowbase * 64;
  const float4v* s0 = (const float4v*)(xp + base);
  const float4v* s1 = (const float4v*)(xp + (size_t)ROWS2 * 64 + base);
  const float4v* s2 = (const float4v*)(xp + (size_t)2 * ROWS2 * 64 + base);
  const float4v* s3 = (const float4v*)(xp + (size_t)3 * ROWS2 * 64 + base);
  float4v* dst = (float4v*)&xs[0][0];
#pragma unroll
  for (int i = 0; i < CLEN / 16; ++i)
    dst[tid + i * 256] = s0[tid + i * 256] + s1[tid + i * 256] +
                         s2[tid + i * 256] + s3[tid + i * 256];
}

// dt = softplus(dot(xs[t][0..31], w2) + bias)
__device__ __forceinline__ float dt_of(const float (*xs)[64], int t,
                                       const f32x2* w2, float bias) {
  f32x2 a2 = {bias, 0.f};
  const f32x2* xr2 = (const f32x2*)&xs[t][0];
#pragma unroll
  for (int j = 0; j < 16; ++j) a2 = pk_fma(xr2[j], w2[j], a2);
  float a = a2.x + a2.y;
  return (a > 15.f) ? a : __logf(1.f + __expf(a));
}

// ---------------- pass 1: dt + local scan + y_loc + S (both dirs) ----------------
// Writes: y_loc (bf16) -> ylg[ubase] (xnyg slot, dead xn), S (bf16) -> uS[ubase]
// (in-place over uh, read-then-write same thread/slot), chunk records -> chk.
__global__ __launch_bounds__(256) void dtscan1_k(u16* uS,
                                                 const float* __restrict__ xp,
                                                 const float* __restrict__ dtw_t,
                                                 const float* __restrict__ dtb,
                                                 const float* __restrict__ alog_,
                                                 const float* __restrict__ Dp,
                                                 int layer,
                                                 u16* __restrict__ ylg,
                                                 float* __restrict__ chk) {
  __shared__ float xs[CLEN][64];                  // 16 kB
  int blk = blockIdx.x;            // 1024 = nb(8) x chunks(32) x dgroup(4)
  int db = blk & 3;
  int c  = (blk >> 2) & (NCHUNK - 1);
  int nb = blk >> 7;               // dir*4 + b
  int dir = nb >> 2;
  int tid = threadIdx.x;
  int d  = db * 256 + tid;
  int li = dir * 2 + layer;
  const float* dtwT = dtw_t + (size_t)li * DTR * DI;
  const float* alog = alog_ + (size_t)li * DI * NST;
  int t0 = c * CLEN;
  size_t rowbase = (size_t)nb * L_ + t0;
  stage_xs(xs, xp, rowbase, tid);
  f32x2 w2[16];
#pragma unroll
  for (int j = 0; j < 16; ++j)
    w2[j] = (f32x2){dtwT[(size_t)(2 * j) * DI + d], dtwT[(size_t)(2 * j + 1) * DI + d]};
  float bias = dtb[(size_t)li * DI + d];
  float Dv = Dp[(size_t)li * DI + d];
  float a20;
  bool fast = a_fast(alog, d, a20);
  __syncthreads();
  float S = 0.f;
  size_t ubase = rowbase * DI + d;
  f32x2 h2[8];
#pragma unroll
  for (int q = 0; q < 8; ++q) h2[q] = (f32x2){0.f, 0.f};
  for (int t = 0; t < CLEN; ++t) {
    float dtv = dt_of(xs, t, w2, bias);
    float uv = bf2f(uS[ubase]);
    float du = dtv * uv;
    S += dtv;
    f32x2 acc2 = {0.f, 0.f};
    if (fast) {
      float p1 = exp2f(dtv * a20);
      float p2 = p1 * p1;
      f32x2 pw = {p1, p2};
      f32x2 pst = {p2, p2};
      f32x2 du2 = {du, du};
#pragma unroll
      for (int k = 0; k < 4; ++k) {
        f32x4 bv = *(const f32x4*)&xs[t][DTR + k * 4];
        f32x4 cv = *(const f32x4*)&xs[t][DTR + NST + k * 4];
        f32x2 blo = __builtin_shufflevector(bv, bv, 0, 1);
        f32x2 bhi = __builtin_shufflevector(bv, bv, 2, 3);
        f32x2 clo = __builtin_shufflevector(cv, cv, 0, 1);
        f32x2 chi = __builtin_shufflevector(cv, cv, 2, 3);
        h2[2 * k]     = pk_fma(pw, h2[2 * k], pk_mul(du2, blo));
        acc2          = pk_fma(h2[2 * k], clo, acc2);
        pw = pk_mul(pw, pst);
        h2[2 * k + 1] = pk_fma(pw, h2[2 * k + 1], pk_mul(du2, bhi));
        acc2          = pk_fma(h2[2 * k + 1], chi, acc2);
        if (k < 3) pw = pk_mul(pw, pst);
      }
    } else {
#pragma unroll
      for (int q = 0; q < 8; ++q) {
        float e0 = exp2f(dtv * -__expf(alog[d * NST + 2 * q]) * LN2R);
        float e1 = exp2f(dtv * -__expf(alog[d * NST + 2 * q + 1]) * LN2R);
        f32x2 bv = *(const f32x2*)&xs[t][DTR + q * 2];
        f32x2 cv = *(const f32x2*)&xs[t][DTR + NST + q * 2];
        h2[q] = pk_fma((f32x2){e0, e1}, h2[q], pk_mul((f32x2){du, du}, bv));
        acc2 = pk_fma(h2[q], cv, acc2);
      }
    }
    float yloc = acc2.x + acc2.y + uv * Dv;
    ylg[ubase] = f2bf(yloc);
    uS[ubase]  = f2bf(S);          // after uv read; same thread, same slot
    ubase += DI;
  }
  const size_t H = (size_t)8 * NCHUNK * DI * NST;
  size_t idx = ((size_t)(nb * NCHUNK + c) * DI + d) * NST;
#pragma unroll
  for (int n = 0; n < NST; ++n) {
    float an = -__expf(alog[d * NST + n]) * LN2R;
    chk[idx + n]     = exp2f(an * S);
    chk[H + idx + n] = (n & 1) ? h2[n >> 1].y : h2[n >> 1].x;
  }
}

// pass 2: sequential chunk combine (both dirs)
__global__ __launch_bounds__(256) void scan2_k(float* __restrict__ chk) {
  int j = blockIdx.x * 256 + threadIdx.x;   // 131072 = 8*DI*NST
  int n = j & 15;
  int d = (j >> 4) & (DI - 1);
  int nb = j >> 14;
  const size_t H = (size_t)8 * NCHUNK * DI * NST;
  float h = 0.f;
  for (int c = 0; c < NCHUNK; ++c) {
    size_t idx = ((size_t)(nb * NCHUNK + c) * DI + d) * NST + n;
    float a = chk[idx];
    float hl = chk[H + idx];
    chk[H + idx] = h;
    h = a * h + hl;
  }
}

// pass 3 (lite): y = y_loc + sum_n C_t[n]*exp2(A2[n]*S_t)*h0[n]; fused gate.
__global__ __launch_bounds__(256) void scan3lite_k(const u16* __restrict__ uS,
                                                   const float* __restrict__ xp,
                                                   const float* __restrict__ alog_,
                                                   int layer,
                                                   const float* __restrict__ chk,
                                                   const u16* __restrict__ xzz,
                                                   u16* ylg) {
  __shared__ float xc[CLEN][NST];                 // 4 kB: C columns only
  int blk = blockIdx.x;
  int db = blk & 3;
  int c  = (blk >> 2) & (NCHUNK - 1);
  int nb = blk >> 7;
  int dir = nb >> 2;
  int tid = threadIdx.x;
  int d  = db * 256 + tid;
  int li = dir * 2 + layer;
  const float* alog = alog_ + (size_t)li * DI * NST;
  int t0 = c * CLEN;
  size_t rowbase = (size_t)nb * L_ + t0;
  {
    int r = tid >> 2, v = tid & 3;                // 64 rows x 4 vec4
    size_t base = (rowbase + r) * 64 + DTR + NST + v * 4;
    float4v s = *(const float4v*)(xp + base)
              + *(const float4v*)(xp + (size_t)ROWS2 * 64 + base)
              + *(const float4v*)(xp + (size_t)2 * ROWS2 * 64 + base)
              + *(const float4v*)(xp + (size_t)3 * ROWS2 * 64 + base);
    *(float4v*)&xc[r][v * 4] = s;
  }
  float a20;
  bool fast = a_fast(alog, d, a20);
  const size_t H = (size_t)8 * NCHUNK * DI * NST;
  size_t cidx = ((size_t)(nb * NCHUNK + c) * DI + d) * NST;
  f32x2 h2[8];
#pragma unroll
  for (int q = 0; q < 8; ++q) h2[q] = *(const f32x2*)&chk[H + cidx + 2 * q];
  float A2g[NST];
  if (!fast) {
#pragma unroll
    for (int n = 0; n < NST; ++n) A2g[n] = -__expf(alog[d * NST + n]) * LN2R;
  }
  __syncthreads();
  size_t ubase = rowbase * DI + d;
  for (int t = 0; t < CLEN; ++t) {
    float S = bf2f(uS[ubase]);
    f32x2 corr2 = {0.f, 0.f};
    if (fast) {
      float w1 = exp2f(a20 * S);
      float w2_ = w1 * w1;
      f32x2 pw = {w1, w2_};
      f32x2 pst = {w2_, w2_};
#pragma unroll
      for (int q = 0; q < 8; ++q) {
        f32x2 cp = *(const f32x2*)&xc[t][2 * q];
        corr2 = pk_fma(pk_mul(pw, h2[q]), cp, corr2);
        if (q < 7) pw = pk_mul(pw, pst);
      }
    } else {
#pragma unroll
      for (int q = 0; q < 8; ++q) {
        f32x2 e = {exp2f(A2g[2 * q] * S), exp2f(A2g[2 * q + 1] * S)};
        f32x2 cp = *(const f32x2*)&xc[t][2 * q];
        corr2 = pk_fma(pk_mul(e, h2[q]), cp, corr2);
      }
    }
    float y = bf2f(ylg[ubase]) + corr2.x + corr2.y;
    float z = bf2f(xzz[ubase]);
    ylg[ubase] = f2bf(y * z * sigmoidf_(z));
    ubase += DI;
  }
}

// ---------------- final rmsnorm(hid+res) -> concat buffer, both dirs ----------------
__global__ __launch_bounds__(256) void fincat_k(const float* __restrict__ hid,
                                                const float* __restrict__ res,
                                                const float* __restrict__ norm_f,
                                                u16* __restrict__ cat) {
  int row = blockIdx.x;                 // 0..16383
  int dir = row >> 13;
  const float* w = norm_f + (size_t)dir * DM;
  int tid = threadIdx.x;
  int base = row * DM;
  float x0 = hid[base + tid] + res[base + tid];
  float x1 = hid[base + 256 + tid] + res[base + 256 + tid];
  float s = x0 * x0 + x1 * x1;
  for (int off = 32; off; off >>= 1) s += __shfl_xor(s, off);
  __shared__ float ps[4];
  if (!(tid & 63)) ps[tid >> 6] = s;
  __syncthreads();
  float tot = ps[0] + ps[1] + ps[2] + ps[3];
  float rs = 1.f / sqrtf(tot / (float)DM + 1e-5f);
  int r = row & (ROWS - 1);
  int b = r >> 11, l = r & (L_ - 1);
  size_t drow = dir ? ((size_t)(b << 11) + (L_ - 1 - l)) : (size_t)r;
  size_t obase = drow * (2 * DM) + (size_t)dir * DM;
  cat[obase + tid]       = f2bf(x0 * rs * w[tid]);
  cat[obase + 256 + tid] = f2bf(x1 * rs * w[tid + 256]);
}

extern "C" void kernel_launch(void* const* d_in, const int* in_sizes, int n_in,
                              void* d_out, int out_size, void* d_ws, size_t ws_size,
                              hipStream_t stream) {
  const int*   ids      = (const int*)d_in[0];
  const float* embed    = (const float*)d_in[2];
  const float* in_w     = (const float*)d_in[3];
  const float* conv_w   = (const float*)d_in[4];
  const float* conv_b   = (const float*)d_in[5];
  const float* x_w      = (const float*)d_in[6];
  const float* dt_w     = (const float*)d_in[7];
  const float* dt_bias  = (const float*)d_in[8];
  const float* A_log    = (const float*)d_in[9];
  const float* Dp       = (const float*)d_in[10];
  const float* out_w    = (const float*)d_in[11];
  const float* norm_w   = (const float*)d_in[12];
  const float* norm_f   = (const float*)d_in[13];
  const float* proj_w   = (const float*)d_in[14];
  const float* proj_b   = (const float*)d_in[15];

  char* ws = (char*)d_ws;
  size_t off = 0;
  auto alloc = [&](size_t bytes) {
    void* p = ws + off;
    off += (bytes + 255) & ~(size_t)255;
    return p;
  };
  float* res  = (float*)alloc((size_t)ROWS2 * DM * 4);       // 33.6 MB
  float* hid  = (float*)alloc((size_t)ROWS2 * DM * 4);       // 33.6 MB (x_proj partials alias)
  u16*   xnyg = (u16*)alloc((size_t)ROWS2 * DI * 2);         // 33.6 MB (xn | y_loc | yg)
  u16*   xzz  = (u16*)alloc((size_t)ROWS2 * DI * 2);         // 33.6 MB (z half)
  void*  shrd = alloc((size_t)ROWS2 * DI * 2);               // 33.6 MB (xzu | chk | cat)
  u16*   u_h  = (u16*)alloc((size_t)ROWS2 * DI * 2);         // 33.6 MB (uh | S)
  const int N_IN  = 4 * 2 * DI * DM;
  const int N_XW  = 4 * 64 * DI;
  const int N_OW  = 4 * DM * DI;
  const int N_PW  = DM * 2 * DM;
  const int N_DTW = 4 * DTR * DI;
  u16*   in_wb  = (u16*)alloc((size_t)N_IN * 2);             //  8.4 MB
  u16*   x_wb   = (u16*)alloc((size_t)N_XW * 2);
  u16*   out_wb = (u16*)alloc((size_t)N_OW * 2);
  u16*   pr_wb  = (u16*)alloc((size_t)N_PW * 2);
  float* dtw_t  = (float*)alloc((size_t)N_DTW * 4);
  if (off > ws_size) return;

  u16*   xzu = (u16*)shrd;
  float* chk = (float*)shrd;
  u16*   cat = (u16*)shrd;

  cvt_k<<<(N_IN / 4 + 255) / 256, 256, 0, stream>>>(in_w, in_wb, N_IN / 4);
  cvt_k<<<(N_XW / 4 + 255) / 256, 256, 0, stream>>>(x_w, x_wb, N_XW / 4);
  cvt_k<<<(N_OW / 4 + 255) / 256, 256, 0, stream>>>(out_w, out_wb, N_OW / 4);
  cvt_k<<<(N_PW / 4 + 255) / 256, 256, 0, stream>>>(proj_w, pr_wb, N_PW / 4);
  trp_k<<<N_DTW / 256, 256, 0, stream>>>(dt_w, dtw_t);

  embed_k<<<ROWS2 * DM / 256, 256, 0, stream>>>(ids, embed, res);
  for (int i = 0; i < 2; ++i) {
    if (i == 0)
      addnorm_k<false><<<ROWS2, 256, 0, stream>>>(res, hid, norm_w, i, xnyg);
    else
      addnorm_k<true><<<ROWS2, 256, 0, stream>>>(res, hid, norm_w, i, xnyg);
    gemm8p_k<<<512, 512, 0, stream>>>(
        xnyg, in_wb + (size_t)i * 2 * DI * DM, xzu, xzz, DM);
    conv_k<<<ROWS2 * DI / 256, 256, 0, stream>>>(xzu, conv_w, conv_b, i, u_h);
    gemm_bt<64, EPI_F32, 4><<<dim3(ROWS2 / 128, 4), 256, 0, stream>>>(
        u_h, x_wb + (size_t)i * 64 * DI, hid, nullptr, 64, DI, (size_t)2 * 64 * DI);
    dtscan1_k<<<1024, 256, 0, stream>>>(u_h, hid, dtw_t, dt_bias, A_log, Dp, i,
                                        xnyg, chk);
    scan2_k<<<512, 256, 0, stream>>>(chk);
    scan3lite_k<<<1024, 256, 0, stream>>>(u_h, hid, A_log, i, chk, xzz, xnyg);
    gemm_bt<64, EPI_F32><<<dim3(ROWS2 / 128, DM / 64), 256, 0, stream>>>(
        xnyg, out_wb + (size_t)i * DM * DI, hid, nullptr, DM, DI, (size_t)2 * DM * DI);
  }
  fincat_k<<<ROWS2, 256, 0, stream>>>(hid, res, norm_f, cat);
  gemm_bt<64, EPI_BIAS><<<dim3(ROWS / 128, DM / 64), 256, 0, stream>>>(
      cat, pr_wb, (float*)d_out, proj_b, DM, DI, 0);
}

// Round 16
// 750.715 us; speedup vs baseline: 1.1226x; 1.0271x over previous
//
#include <hip/hip_runtime.h>
#include <hip/hip_bf16.h>

#define B_   4
#define L_   2048
#define DM   512
#define DI   1024
#define NST  16
#define DTR  32
#define ROWS  (B_ * L_)        // 8192
#define ROWS2 (2 * ROWS)       // 16384 (both directions)
#define NCHUNK 32
#define CLEN  (L_ / NCHUNK)    // 64
#define LN2R 1.4426950408889634f

typedef unsigned short u16;
typedef __attribute__((ext_vector_type(8))) short bf16x8;
typedef __attribute__((ext_vector_type(4))) float f32x4;
typedef __attribute__((ext_vector_type(4))) float float4v;
typedef __attribute__((ext_vector_type(2))) float f32x2;

__device__ __forceinline__ float bf2f(u16 h) {
  union { unsigned int u; float f; } v; v.u = ((unsigned int)h) << 16; return v.f;
}
__device__ __forceinline__ u16 f2bf(float f) {
  union { float f; unsigned int u; } v; v.f = f;
  unsigned int u = v.u;
  if ((u & 0x7fffffffu) > 0x7f800000u) return (u16)((u >> 16) | 0x0040u);
  return (u16)((u + 0x7fffu + ((u >> 16) & 1u)) >> 16);
}
__device__ __forceinline__ float sigmoidf_(float x) { return 1.f / (1.f + __expf(-x)); }

__device__ __forceinline__ f32x2 pk_mul(f32x2 a, f32x2 b) {
  f32x2 d; asm("v_pk_mul_f32 %0, %1, %2" : "=v"(d) : "v"(a), "v"(b)); return d;
}
__device__ __forceinline__ f32x2 pk_fma(f32x2 a, f32x2 b, f32x2 c) {
  f32x2 d; asm("v_pk_fma_f32 %0, %1, %2, %3" : "=v"(d) : "v"(a), "v"(b), "v"(c)); return d;
}

__device__ __forceinline__ void gload16(const u16* g, u16* l) {
  __builtin_amdgcn_global_load_lds(
      (const __attribute__((address_space(1))) void*)g,
      (__attribute__((address_space(3))) void*)l, 16, 0, 0);
}

// ---------------- f32 -> bf16 weight conversion ----------------
__global__ __launch_bounds__(256) void cvt_k(const float* __restrict__ in,
                                             u16* __restrict__ out, int n4) {
  int i = blockIdx.x * 256 + threadIdx.x;
  if (i >= n4) return;
  float4v v = *(const float4v*)&in[i * 4];
  u16 o[4];
  o[0] = f2bf(v.x); o[1] = f2bf(v.y); o[2] = f2bf(v.z); o[3] = f2bf(v.w);
  *(ulong1*)&out[i * 4] = *(ulong1*)o;
}

// ---------------- dt_w transpose: [4][DI][DTR] -> [4][DTR][DI] (f32) ----------------
__global__ __launch_bounds__(256) void trp_k(const float* __restrict__ in,
                                             float* __restrict__ out) {
  int o = blockIdx.x * 256 + threadIdx.x;
  int li = o >> 15;
  int k = (o >> 10) & (DTR - 1);
  int d = o & (DI - 1);
  out[o] = in[((size_t)li * DI + d) * DTR + k];
}

// ---------------- embed gather, both directions ----------------
__global__ __launch_bounds__(256) void embed_k(const int* __restrict__ ids,
                                               const float* __restrict__ emb,
                                               float* __restrict__ res) {
  int idx = blockIdx.x * 256 + threadIdx.x;   // ROWS2*DM
  int c = idx & (DM - 1);
  int row = idx >> 9;                          // 0..16383
  int dir = row >> 13;
  int r = row & (ROWS - 1);
  int b = r >> 11;
  int l = r & (L_ - 1);
  int sl = dir ? (L_ - 1 - l) : l;
  int id = ids[(b << 11) + sl];
  res[idx] = emb[(size_t)dir * 128 * DM + id * DM + c];
}

// ---------------- (res += hid); xn = rmsnorm(res) * w (per-dir weights) ----------------
template <bool ADD>
__global__ __launch_bounds__(256) void addnorm_k(float* __restrict__ res,
                                                 const float* __restrict__ hid,
                                                 const float* __restrict__ norm_w,
                                                 int layer,
                                                 u16* __restrict__ xn) {
  int row = blockIdx.x;                        // 0..16383
  int dir = row >> 13;
  const float* w = norm_w + (size_t)(dir * 2 + layer) * DM;
  int tid = threadIdx.x;
  int base = row * DM;
  float x0 = res[base + tid];
  float x1 = res[base + 256 + tid];
  if (ADD) {
    x0 += hid[base + tid];
    x1 += hid[base + 256 + tid];
    res[base + tid] = x0;
    res[base + 256 + tid] = x1;
  }
  float s = x0 * x0 + x1 * x1;
  for (int off = 32; off; off >>= 1) s += __shfl_xor(s, off);
  __shared__ float ps[4];
  if (!(tid & 63)) ps[tid >> 6] = s;
  __syncthreads();
  float tot = ps[0] + ps[1] + ps[2] + ps[3];
  float rs = 1.f / sqrtf(tot / (float)DM + 1e-5f);
  xn[base + tid]       = f2bf(x0 * rs * w[tid]);
  xn[base + 256 + tid] = f2bf(x1 * rs * w[tid + 256]);
}

// ---------------- in_proj: 256x256 tile, BK=32, 2 buffers (64 kB LDS -> 2 blk/CU) ----------------
// Per tau: stage(tau+1) -> counted vmcnt(4) -> barrier -> 32 MFMA -> lgkm drain -> barrier.
// Cross-block wave overlap (2 blocks/CU) hides the barrier/drain stalls.
#define MFMA_B16(a, b, c) __builtin_amdgcn_mfma_f32_16x16x32_bf16(a, b, c, 0, 0, 0)

__global__ __launch_bounds__(512) void g256_k(const u16* __restrict__ A,
                                              const u16* __restrict__ W,   // layer base (dir0)
                                              u16* __restrict__ outU,
                                              u16* __restrict__ outZ,
                                              int K) {
  __shared__ u16 As[2][256 * 32];   // 32 kB
  __shared__ u16 Wsh[2][256 * 32];  // 32 kB
  int tid = threadIdx.x;
  int lane = tid & 63;
  int wv = tid >> 6;
  int wr = wv >> 2, wc = wv & 3;    // 2M x 4N waves
  int bid = blockIdx.x;             // 512 blocks: 64 mt x 8 nt
  int xcd = bid & 7, jj = bid >> 3;
  int mt = xcd * 8 + (jj & 7);      // 0..63
  int nt = jj >> 3;                 // 0..7
  int m0 = mt * 256, n0 = nt * 256;
  const u16* Weff = W + (size_t)(m0 >> 13) * (size_t)2 * (2 * DI) * DM;
  f32x4 acc[8][4];
#pragma unroll
  for (int i = 0; i < 8; ++i)
#pragma unroll
    for (int j = 0; j < 4; ++j) acc[i][j] = (f32x4){0.f, 0.f, 0.f, 0.f};
  int rr = lane & 15;
  int sl = lane >> 4;
  int pofs = ((sl + (rr >> 1)) & 3) * 8;    // conflict-free swizzled read slot
  int lr = lane >> 2;
  int ls = ((lane & 3) - (lr >> 1)) & 3;    // matching pre-swizzled source slot

  auto stage = [&](int tau, int buf) {
#pragma unroll
    for (int j = 0; j < 2; ++j) {
      gload16(A + (size_t)(m0 + j * 128 + wv * 16 + lr) * K + tau * 32 + ls * 8,
              &As[buf][(j * 128 + wv * 16) * 32]);
      gload16(Weff + (size_t)(n0 + j * 128 + wv * 16 + lr) * K + tau * 32 + ls * 8,
              &Wsh[buf][(j * 128 + wv * 16) * 32]);
    }
  };

  int NK = K / 32;                  // 16
  stage(0, 0);
  for (int tau = 0; tau < NK; ++tau) {
    int buf = tau & 1;
    bool more = (tau + 1 < NK);
    if (more) stage(tau + 1, buf ^ 1);     // buf^1 held tile tau-1; reads drained last barrier
    if (more)
      asm volatile("s_waitcnt vmcnt(4)" ::: "memory");   // tau's 4 loads done; tau+1 in flight
    else
      asm volatile("s_waitcnt vmcnt(0)" ::: "memory");
    __builtin_amdgcn_sched_barrier(0);
    __builtin_amdgcn_s_barrier();          // cross-wave: tile tau fully in LDS
    __builtin_amdgcn_sched_barrier(0);
    bf16x8 af[8], wf[4];
#pragma unroll
    for (int mi = 0; mi < 8; ++mi)
      af[mi] = *(bf16x8*)&As[buf][(wr * 128 + mi * 16 + rr) * 32 + pofs];
#pragma unroll
    for (int ni = 0; ni < 4; ++ni)
      wf[ni] = *(bf16x8*)&Wsh[buf][(wc * 64 + ni * 16 + rr) * 32 + pofs];
    __builtin_amdgcn_s_setprio(1);
#pragma unroll
    for (int mi = 0; mi < 8; ++mi)
#pragma unroll
      for (int ni = 0; ni < 4; ++ni)
        acc[mi][ni] = MFMA_B16(af[mi], wf[ni], acc[mi][ni]);
    __builtin_amdgcn_s_setprio(0);
    asm volatile("s_waitcnt lgkmcnt(0)" ::: "memory");
    __builtin_amdgcn_sched_barrier(0);
    __builtin_amdgcn_s_barrier();          // all waves done reading buf
    __builtin_amdgcn_sched_barrier(0);
  }
  int cr = (lane >> 4) << 2;
  int cc = lane & 15;
  u16* outp = (n0 < DI) ? outU : outZ;
  int cb0 = (n0 < DI) ? n0 : (n0 - DI);
#pragma unroll
  for (int mi = 0; mi < 8; ++mi)
#pragma unroll
    for (int ni = 0; ni < 4; ++ni) {
      int row = m0 + wr * 128 + mi * 16 + cr;
      int col = cb0 + wc * 64 + ni * 16 + cc;
#pragma unroll
      for (int j = 0; j < 4; ++j)
        outp[(size_t)(row + j) * DI + col] = f2bf(acc[mi][ni][j]);
    }
}

// ---------------- GEMM (generic): 4-ring, stage-ahead-3, per-dir weight stride ----------------
#define EPI_F32  0
#define EPI_BF16 1
#define EPI_BIAS 2

template <int BN, int EPI, int SK = 1>
__global__ __launch_bounds__(256) void gemm_bt(const u16* __restrict__ A,
                                               const u16* __restrict__ W,
                                               void* __restrict__ outp,
                                               const float* __restrict__ bias,
                                               int N, int K, size_t wsd) {
  constexpr int BM = 128, BK = 32;
  constexpr int NF = BN / 32;
  constexpr int G = (BN == 128) ? 4 : 3;
  __shared__ u16 As[4][BM * BK];
  __shared__ u16 Wsh[4][BN * BK];
  int tid = threadIdx.x;
  int lane = tid & 63;
  int wv = tid >> 6;
  int wr = wv >> 1, wc = wv & 1;
  int m0 = blockIdx.x * BM;
  int n0 = (SK > 1) ? 0 : blockIdx.y * BN;
  int koff = (SK > 1) ? blockIdx.y * (K / SK) : 0;
  int KS = K / SK;
  int NK = KS / BK;
  const u16* Weff = W + (size_t)(m0 >> 13) * wsd;
  f32x4 acc[4][NF];
#pragma unroll
  for (int i = 0; i < 4; ++i)
#pragma unroll
    for (int j = 0; j < NF; ++j) acc[i][j] = (f32x4){0.f, 0.f, 0.f, 0.f};
  int rr = lane & 15;
  int kk = (lane >> 4) << 3;
  int l4 = lane >> 2;
  int c8 = (lane & 3) << 3;
  const u16* Ag = A + (size_t)(m0 + l4) * K + koff + c8;
  const u16* Wg = Weff + (size_t)(n0 + l4) * K + koff + c8;

  auto stage = [&](int k0, int buf) {
    gload16(Ag + (size_t)(wv * 16) * K + k0, &As[buf][wv * 512]);
    gload16(Ag + (size_t)((wv + 4) * 16) * K + k0, &As[buf][(wv + 4) * 512]);
    gload16(Wg + (size_t)(wv * 16) * K + k0, &Wsh[buf][wv * 512]);
    if (BN == 128)
      gload16(Wg + (size_t)((wv + 4) * 16) * K + k0, &Wsh[buf][(wv + 4) * 512]);
  };

  stage(0, 0); stage(BK, 1); stage(2 * BK, 2);
  for (int k = 0; k < NK; ++k) {
    if (k < NK - 2)
      asm volatile("s_waitcnt vmcnt(%0)" :: "n"(2 * G) : "memory");
    else if (k == NK - 2)
      asm volatile("s_waitcnt vmcnt(%0)" :: "n"(G) : "memory");
    else
      asm volatile("s_waitcnt vmcnt(0)" ::: "memory");
    __builtin_amdgcn_s_barrier();
    __builtin_amdgcn_sched_barrier(0);
    if (k + 3 < NK) stage((k + 3) * BK, (k + 3) & 3);
    __builtin_amdgcn_sched_barrier(0);
    int cur = k & 3;
    bf16x8 af[4], wf[NF];
#pragma unroll
    for (int mi = 0; mi < 4; ++mi)
      af[mi] = *(bf16x8*)&As[cur][(wr * 64 + mi * 16 + rr) * BK + kk];
#pragma unroll
    for (int ni = 0; ni < NF; ++ni)
      wf[ni] = *(bf16x8*)&Wsh[cur][(wc * (BN / 2) + ni * 16 + rr) * BK + kk];
#pragma unroll
    for (int mi = 0; mi < 4; ++mi)
#pragma unroll
      for (int ni = 0; ni < NF; ++ni)
        acc[mi][ni] = __builtin_amdgcn_mfma_f32_16x16x32_bf16(af[mi], wf[ni], acc[mi][ni], 0, 0, 0);
  }
  int cr = (lane >> 4) << 2;
  int cc = lane & 15;
  float* outF = (float*)outp +
      ((SK > 1) ? (size_t)blockIdx.y * (size_t)gridDim.x * BM * N : 0);
#pragma unroll
  for (int mi = 0; mi < 4; ++mi)
#pragma unroll
    for (int ni = 0; ni < NF; ++ni) {
      int row = m0 + wr * 64 + mi * 16 + cr;
      int col = n0 + wc * (BN / 2) + ni * 16 + cc;
      float bv = (EPI == EPI_BIAS) ? bias[col] : 0.f;
#pragma unroll
      for (int j = 0; j < 4; ++j) {
        float v = acc[mi][ni][j] + bv;
        if (EPI == EPI_BF16)
          ((u16*)outp)[(size_t)(row + j) * N + col] = f2bf(v);
        else
          outF[(size_t)(row + j) * N + col] = v;
      }
    }
}

// ---------------- depthwise causal conv + SiLU, both dirs ----------------
__global__ __launch_bounds__(256) void conv_k(const u16* __restrict__ xzu,
                                              const float* __restrict__ conv_w,
                                              const float* __restrict__ conv_b,
                                              int layer,
                                              u16* __restrict__ uh) {
  int idx = blockIdx.x * 256 + threadIdx.x;        // ROWS2*DI
  int c = idx & (DI - 1);
  int row = idx >> 10;
  int dir = row >> 13;
  int l = row & (L_ - 1);
  const float* cw = conv_w + (size_t)(dir * 2 + layer) * DI * 4;
  const float* cb = conv_b + (size_t)(dir * 2 + layer) * DI;
  float acc = cb[c];
#pragma unroll
  for (int j = 0; j < 4; ++j) {
    int ls = l + j - 3;
    if (ls >= 0)
      acc += bf2f(xzu[(size_t)(row + j - 3) * DI + c]) * cw[c * 4 + j];
  }
  float s = acc * sigmoidf_(acc);
  uh[idx] = f2bf(s);
}

// A-structure check
__device__ __forceinline__ bool a_fast(const float* alog, int d, float& a20) {
  a20 = -__expf(alog[d * NST]) * LN2R;
  bool fast = true;
#pragma unroll
  for (int n = 1; n < NST; ++n) {
    float an = -__expf(alog[d * NST + n]) * LN2R;
    fast &= (fabsf(an - (float)(n + 1) * a20) <= 1e-5f * (float)(n + 1) * fabsf(a20));
  }
  return fast;
}

// stage xs[CLEN][64] by summing 4 x_proj split-K partials (rowbase in rows)
__device__ __forceinline__ void stage_xs(float (*xs)[64], const float* xp,
                                         size_t rowbase, int tid) {
  size_t base = rowbase * 64;
  const float4v* s0 = (const float4v*)(xp + base);
  const float4v* s1 = (const float4v*)(xp + (size_t)ROWS2 * 64 + base);
  const float4v* s2 = (const float4v*)(xp + (size_t)2 * ROWS2 * 64 + base);
  const float4v* s3 = (const float4v*)(xp + (size_t)3 * ROWS2 * 64 + base);
  float4v* dst = (float4v*)&xs[0][0];
#pragma unroll
  for (int i = 0; i < CLEN / 16; ++i)
    dst[tid + i * 256] = s0[tid + i * 256] + s1[tid + i * 256] +
                         s2[tid + i * 256] + s3[tid + i * 256];
}

// dt = softplus(dot(xs[t][0..31], w2) + bias), 4 independent accumulator chains
__device__ __forceinline__ float dt_of(const float (*xs)[64], int t,
                                       const f32x2* w2, float bias) {
  const f32x2* x = (const f32x2*)&xs[t][0];
  f32x2 a0 = {bias, 0.f}, a1 = {0.f, 0.f}, a2 = {0.f, 0.f}, a3 = {0.f, 0.f};
#pragma unroll
  for (int j = 0; j < 4; ++j) {
    a0 = pk_fma(x[4 * j],     w2[4 * j],     a0);
    a1 = pk_fma(x[4 * j + 1], w2[4 * j + 1], a1);
    a2 = pk_fma(x[4 * j + 2], w2[4 * j + 2], a2);
    a3 = pk_fma(x[4 * j + 3], w2[4 * j + 3], a3);
  }
  float a = (a0.x + a0.y) + (a1.x + a1.y) + ((a2.x + a2.y) + (a3.x + a3.y));
  return (a > 15.f) ? a : __logf(1.f + __expf(a));
}

// ---------------- pass 1: dt + local scan + y_loc + S (both dirs) ----------------
__global__ __launch_bounds__(256) void dtscan1_k(u16* uS,
                                                 const float* __restrict__ xp,
                                                 const float* __restrict__ dtw_t,
                                                 const float* __restrict__ dtb,
                                                 const float* __restrict__ alog_,
                                                 const float* __restrict__ Dp,
                                                 int layer,
                                                 u16* __restrict__ ylg,
                                                 float* __restrict__ chk) {
  __shared__ float xs[CLEN][64];                  // 16 kB
  int blk = blockIdx.x;            // 1024 = nb(8) x chunks(32) x dgroup(4)
  int db = blk & 3;
  int c  = (blk >> 2) & (NCHUNK - 1);
  int nb = blk >> 7;               // dir*4 + b
  int dir = nb >> 2;
  int tid = threadIdx.x;
  int d  = db * 256 + tid;
  int li = dir * 2 + layer;
  const float* dtwT = dtw_t + (size_t)li * DTR * DI;
  const float* alog = alog_ + (size_t)li * DI * NST;
  int t0 = c * CLEN;
  size_t rowbase = (size_t)nb * L_ + t0;
  stage_xs(xs, xp, rowbase, tid);
  f32x2 w2[16];
#pragma unroll
  for (int j = 0; j < 16; ++j)
    w2[j] = (f32x2){dtwT[(size_t)(2 * j) * DI + d], dtwT[(size_t)(2 * j + 1) * DI + d]};
  float bias = dtb[(size_t)li * DI + d];
  float Dv = Dp[(size_t)li * DI + d];
  float a20;
  bool fast = a_fast(alog, d, a20);
  __syncthreads();
  float S = 0.f;
  size_t ubase = rowbase * DI + d;
  f32x2 h2[8];
#pragma unroll
  for (int q = 0; q < 8; ++q) h2[q] = (f32x2){0.f, 0.f};
  float uv = bf2f(uS[ubase]);
  for (int t = 0; t < CLEN; ++t) {
    float uv_nx = (t + 1 < CLEN) ? bf2f(uS[ubase + DI]) : 0.f;
    float dtv = dt_of(xs, t, w2, bias);
    float du = dtv * uv;
    S += dtv;
    f32x2 accA = {0.f, 0.f}, accB = {0.f, 0.f};
    if (fast) {
      float p1 = exp2f(dtv * a20);
      float p2 = p1 * p1;
      f32x2 pw = {p1, p2};
      f32x2 pst = {p2, p2};
      f32x2 du2 = {du, du};
#pragma unroll
      for (int k = 0; k < 4; ++k) {
        f32x4 bv = *(const f32x4*)&xs[t][DTR + k * 4];
        f32x4 cv = *(const f32x4*)&xs[t][DTR + NST + k * 4];
        f32x2 blo = __builtin_shufflevector(bv, bv, 0, 1);
        f32x2 bhi = __builtin_shufflevector(bv, bv, 2, 3);
        f32x2 clo = __builtin_shufflevector(cv, cv, 0, 1);
        f32x2 chi = __builtin_shufflevector(cv, cv, 2, 3);
        h2[2 * k]     = pk_fma(pw, h2[2 * k], pk_mul(du2, blo));
        accA          = pk_fma(h2[2 * k], clo, accA);
        pw = pk_mul(pw, pst);
        h2[2 * k + 1] = pk_fma(pw, h2[2 * k + 1], pk_mul(du2, bhi));
        accB          = pk_fma(h2[2 * k + 1], chi, accB);
        if (k < 3) pw = pk_mul(pw, pst);
      }
    } else {
#pragma unroll
      for (int q = 0; q < 8; ++q) {
        float e0 = exp2f(dtv * -__expf(alog[d * NST + 2 * q]) * LN2R);
        float e1 = exp2f(dtv * -__expf(alog[d * NST + 2 * q + 1]) * LN2R);
        f32x2 bv = *(const f32x2*)&xs[t][DTR + q * 2];
        f32x2 cv = *(const f32x2*)&xs[t][DTR + NST + q * 2];
        h2[q] = pk_fma((f32x2){e0, e1}, h2[q], pk_mul((f32x2){du, du}, bv));
        if (q & 1) accB = pk_fma(h2[q], cv, accB);
        else       accA = pk_fma(h2[q], cv, accA);
      }
    }
    float yloc = (accA.x + accA.y) + (accB.x + accB.y) + uv * Dv;
    ylg[ubase] = f2bf(yloc);
    uS[ubase]  = f2bf(S);          // after uv read; same thread, same slot
    uv = uv_nx;
    ubase += DI;
  }
  const size_t H = (size_t)8 * NCHUNK * DI * NST;
  size_t idx = ((size_t)(nb * NCHUNK + c) * DI + d) * NST;
#pragma unroll
  for (int n = 0; n < NST; ++n) {
    float an = -__expf(alog[d * NST + n]) * LN2R;
    chk[idx + n]     = exp2f(an * S);
    chk[H + idx + n] = (n & 1) ? h2[n >> 1].y : h2[n >> 1].x;
  }
}

// pass 2: sequential chunk combine (both dirs)
__global__ __launch_bounds__(256) void scan2_k(float* __restrict__ chk) {
  int j = blockIdx.x * 256 + threadIdx.x;   // 131072 = 8*DI*NST
  int n = j & 15;
  int d = (j >> 4) & (DI - 1);
  int nb = j >> 14;
  const size_t H = (size_t)8 * NCHUNK * DI * NST;
  float h = 0.f;
  for (int c = 0; c < NCHUNK; ++c) {
    size_t idx = ((size_t)(nb * NCHUNK + c) * DI + d) * NST + n;
    float a = chk[idx];
    float hl = chk[H + idx];
    chk[H + idx] = h;
    h = a * h + hl;
  }
}

// pass 3 (lite): y = y_loc + sum_n C_t[n]*exp2(A2[n]*S_t)*h0[n]; fused gate.
__global__ __launch_bounds__(256) void scan3lite_k(const u16* __restrict__ uS,
                                                   const float* __restrict__ xp,
                                                   const float* __restrict__ alog_,
                                                   int layer,
                                                   const float* __restrict__ chk,
                                                   const u16* __restrict__ xzz,
                                                   u16* ylg) {
  __shared__ float xc[CLEN][NST];                 // 4 kB: C columns only
  int blk = blockIdx.x;
  int db = blk & 3;
  int c  = (blk >> 2) & (NCHUNK - 1);
  int nb = blk >> 7;
  int dir = nb >> 2;
  int tid = threadIdx.x;
  int d  = db * 256 + tid;
  int li = dir * 2 + layer;
  const float* alog = alog_ + (size_t)li * DI * NST;
  int t0 = c * CLEN;
  size_t rowbase = (size_t)nb * L_ + t0;
  {
    int r = tid >> 2, v = tid & 3;                // 64 rows x 4 vec4
    size_t base = (rowbase + r) * 64 + DTR + NST + v * 4;
    float4v s = *(const float4v*)(xp + base)
              + *(const float4v*)(xp + (size_t)ROWS2 * 64 + base)
              + *(const float4v*)(xp + (size_t)2 * ROWS2 * 64 + base)
              + *(const float4v*)(xp + (size_t)3 * ROWS2 * 64 + base);
    *(float4v*)&xc[r][v * 4] = s;
  }
  float a20;
  bool fast = a_fast(alog, d, a20);
  const size_t H = (size_t)8 * NCHUNK * DI * NST;
  size_t cidx = ((size_t)(nb * NCHUNK + c) * DI + d) * NST;
  f32x2 h2[8];
#pragma unroll
  for (int q = 0; q < 8; ++q) h2[q] = *(const f32x2*)&chk[H + cidx + 2 * q];
  float A2g[NST];
  if (!fast) {
#pragma unroll
    for (int n = 0; n < NST; ++n) A2g[n] = -__expf(alog[d * NST + n]) * LN2R;
  }
  __syncthreads();
  size_t ubase = rowbase * DI + d;
  float S = bf2f(uS[ubase]);
  for (int t = 0; t < CLEN; ++t) {
    float S_nx = (t + 1 < CLEN) ? bf2f(uS[ubase + DI]) : 0.f;
    f32x2 corrA = {0.f, 0.f}, corrB = {0.f, 0.f};
    if (fast) {
      float w1 = exp2f(a20 * S);
      float w2_ = w1 * w1;
      f32x2 pw = {w1, w2_};
      f32x2 pst = {w2_, w2_};
#pragma unroll
      for (int q = 0; q < 8; ++q) {
        f32x2 cp = *(const f32x2*)&xc[t][2 * q];
        if (q & 1) corrB = pk_fma(pk_mul(pw, h2[q]), cp, corrB);
        else       corrA = pk_fma(pk_mul(pw, h2[q]), cp, corrA);
        if (q < 7) pw = pk_mul(pw, pst);
      }
    } else {
#pragma unroll
      for (int q = 0; q < 8; ++q) {
        f32x2 e = {exp2f(A2g[2 * q] * S), exp2f(A2g[2 * q + 1] * S)};
        f32x2 cp = *(const f32x2*)&xc[t][2 * q];
        if (q & 1) corrB = pk_fma(pk_mul(e, h2[q]), cp, corrB);
        else       corrA = pk_fma(pk_mul(e, h2[q]), cp, corrA);
      }
    }
    float y = bf2f(ylg[ubase]) + (corrA.x + corrA.y) + (corrB.x + corrB.y);
    float z = bf2f(xzz[ubase]);
    ylg[ubase] = f2bf(y * z * sigmoidf_(z));
    S = S_nx;
    ubase += DI;
  }
}

// ---------------- final rmsnorm(hid+res) -> concat buffer, both dirs ----------------
__global__ __launch_bounds__(256) void fincat_k(const float* __restrict__ hid,
                                                const float* __restrict__ res,
                                                const float* __restrict__ norm_f,
                                                u16* __restrict__ cat) {
  int row = blockIdx.x;                 // 0..16383
  int dir = row >> 13;
  const float* w = norm_f + (size_t)dir * DM;
  int tid = threadIdx.x;
  int base = row * DM;
  float x0 = hid[base + tid] + res[base + tid];
  float x1 = hid[base + 256 + tid] + res[base + 256 + tid];
  float s = x0 * x0 + x1 * x1;
  for (int off = 32; off; off >>= 1) s += __shfl_xor(s, off);
  __shared__ float ps[4];
  if (!(tid & 63)) ps[tid >> 6] = s;
  __syncthreads();
  float tot = ps[0] + ps[1] + ps[2] + ps[3];
  float rs = 1.f / sqrtf(tot / (float)DM + 1e-5f);
  int r = row & (ROWS - 1);
  int b = r >> 11, l = r & (L_ - 1);
  size_t drow = dir ? ((size_t)(b << 11) + (L_ - 1 - l)) : (size_t)r;
  size_t obase = drow * (2 * DM) + (size_t)dir * DM;
  cat[obase + tid]       = f2bf(x0 * rs * w[tid]);
  cat[obase + 256 + tid] = f2bf(x1 * rs * w[tid + 256]);
}

extern "C" void kernel_launch(void* const* d_in, const int* in_sizes, int n_in,
                              void* d_out, int out_size, void* d_ws, size_t ws_size,
                              hipStream_t stream) {
  const int*   ids      = (const int*)d_in[0];
  const float* embed    = (const float*)d_in[2];
  const float* in_w     = (const float*)d_in[3];
  const float* conv_w   = (const float*)d_in[4];
  const float* conv_b   = (const float*)d_in[5];
  const float* x_w      = (const float*)d_in[6];
  const float* dt_w     = (const float*)d_in[7];
  const float* dt_bias  = (const float*)d_in[8];
  const float* A_log    = (const float*)d_in[9];
  const float* Dp       = (const float*)d_in[10];
  const float* out_w    = (const float*)d_in[11];
  const float* norm_w   = (const float*)d_in[12];
  const float* norm_f   = (const float*)d_in[13];
  const float* proj_w   = (const float*)d_in[14];
  const float* proj_b   = (const float*)d_in[15];

  char* ws = (char*)d_ws;
  size_t off = 0;
  auto alloc = [&](size_t bytes) {
    void* p = ws + off;
    off += (bytes + 255) & ~(size_t)255;
    return p;
  };
  float* res  = (float*)alloc((size_t)ROWS2 * DM * 4);       // 33.6 MB
  float* hid  = (float*)alloc((size_t)ROWS2 * DM * 4);       // 33.6 MB (x_proj partials alias)
  u16*   xnyg = (u16*)alloc((size_t)ROWS2 * DI * 2);         // 33.6 MB (xn | y_loc | yg)
  u16*   xzz  = (u16*)alloc((size_t)ROWS2 * DI * 2);         // 33.6 MB (z half)
  void*  shrd = alloc((size_t)ROWS2 * DI * 2);               // 33.6 MB (xzu | chk | cat)
  u16*   u_h  = (u16*)alloc((size_t)ROWS2 * DI * 2);         // 33.6 MB (uh | S)
  const int N_IN  = 4 * 2 * DI * DM;
  const int N_XW  = 4 * 64 * DI;
  const int N_OW  = 4 * DM * DI;
  const int N_PW  = DM * 2 * DM;
  const int N_DTW = 4 * DTR * DI;
  u16*   in_wb  = (u16*)alloc((size_t)N_IN * 2);             //  8.4 MB
  u16*   x_wb   = (u16*)alloc((size_t)N_XW * 2);
  u16*   out_wb = (u16*)alloc((size_t)N_OW * 2);
  u16*   pr_wb  = (u16*)alloc((size_t)N_PW * 2);
  float* dtw_t  = (float*)alloc((size_t)N_DTW * 4);
  if (off > ws_size) return;

  u16*   xzu = (u16*)shrd;
  float* chk = (float*)shrd;
  u16*   cat = (u16*)shrd;

  cvt_k<<<(N_IN / 4 + 255) / 256, 256, 0, stream>>>(in_w, in_wb, N_IN / 4);
  cvt_k<<<(N_XW / 4 + 255) / 256, 256, 0, stream>>>(x_w, x_wb, N_XW / 4);
  cvt_k<<<(N_OW / 4 + 255) / 256, 256, 0, stream>>>(out_w, out_wb, N_OW / 4);
  cvt_k<<<(N_PW / 4 + 255) / 256, 256, 0, stream>>>(proj_w, pr_wb, N_PW / 4);
  trp_k<<<N_DTW / 256, 256, 0, stream>>>(dt_w, dtw_t);

  embed_k<<<ROWS2 * DM / 256, 256, 0, stream>>>(ids, embed, res);
  for (int i = 0; i < 2; ++i) {
    if (i == 0)
      addnorm_k<false><<<ROWS2, 256, 0, stream>>>(res, hid, norm_w, i, xnyg);
    else
      addnorm_k<true><<<ROWS2, 256, 0, stream>>>(res, hid, norm_w, i, xnyg);
    g256_k<<<512, 512, 0, stream>>>(
        xnyg, in_wb + (size_t)i * 2 * DI * DM, xzu, xzz, DM);
    conv_k<<<ROWS2 * DI / 256, 256, 0, stream>>>(xzu, conv_w, conv_b, i, u_h);
    gemm_bt<64, EPI_F32, 4><<<dim3(ROWS2 / 128, 4), 256, 0, stream>>>(
        u_h, x_wb + (size_t)i * 64 * DI, hid, nullptr, 64, DI, (size_t)2 * 64 * DI);
    dtscan1_k<<<1024, 256, 0, stream>>>(u_h, hid, dtw_t, dt_bias, A_log, Dp, i,
                                        xnyg, chk);
    scan2_k<<<512, 256, 0, stream>>>(chk);
    scan3lite_k<<<1024, 256, 0, stream>>>(u_h, hid, A_log, i, chk, xzz, xnyg);
    gemm_bt<64, EPI_F32><<<dim3(ROWS2 / 128, DM / 64), 256, 0, stream>>>(
        xnyg, out_wb + (size_t)i * DM * DI, hid, nullptr, DM, DI, (size_t)2 * DM * DI);
  }
  fincat_k<<<ROWS2, 256, 0, stream>>>(hid, res, norm_f, cat);
  gemm_bt<64, EPI_BIAS><<<dim3(ROWS / 128, DM / 64), 256, 0, stream>>>(
      cat, pr_wb, (float*)d_out, proj_b, DM, DI, 0);
}